// Round 1
// baseline (808.572 us; speedup 1.0000x reference)
//
#include <hip/hip_runtime.h>

#define NB    16
#define NN    4096
#define NNODE (NB*NN)   // 65536
#define HD    128
#define NE    524288

// ===================== init: h0 = relu([embed|coords] @ W_in + b_in) * vf =====================
__global__ void init_k(const int* __restrict__ types, const float* __restrict__ coords,
                       const unsigned char* __restrict__ maskb,
                       const float* __restrict__ embed, const float* __restrict__ W_in,
                       const float* __restrict__ b_in, float* __restrict__ hf)
{
    int half = threadIdx.x >> 7;
    int c    = threadIdx.x & 127;
    int node = blockIdx.x * 2 + half;
    __shared__ float xs[2][8];
    if (c < 4)      xs[half][c] = embed[(size_t)types[node] * 4 + c];
    else if (c < 7) xs[half][c] = coords[(size_t)node * 3 + (c - 4)];
    __syncthreads();
    float acc = b_in[c];
#pragma unroll
    for (int k = 0; k < 7; ++k) acc += xs[half][k] * W_in[k * HD + c];
    hf[(size_t)node * HD + c] = maskb[node] ? 0.f : fmaxf(acc, 0.f);
}

// ===================== CSR build (by dst), reused for both rounds =====================
__global__ void deg_k(const int* __restrict__ adj, const int* __restrict__ ebi, int* __restrict__ deg)
{
    int e = blockIdx.x * 256 + threadIdx.x;
    int d = ebi[e] * NN + adj[2 * e + 1];
    atomicAdd(&deg[d], 1);
}

__global__ void scan_k(const int* __restrict__ deg, int* __restrict__ offs)
{
    __shared__ int sums[1024];
    int t = threadIdx.x;
    int base = t * 64;
    int s = 0;
    for (int i = 0; i < 64; ++i) s += deg[base + i];
    sums[t] = s;
    __syncthreads();
    for (int off = 1; off < 1024; off <<= 1) {
        int add = (t >= off) ? sums[t - off] : 0;
        __syncthreads();
        sums[t] += add;
        __syncthreads();
    }
    int run = (t > 0) ? sums[t - 1] : 0;   // exclusive
    for (int i = 0; i < 64; ++i) { offs[base + i] = run; run += deg[base + i]; }
    if (t == 1023) offs[NNODE] = run;
}

__global__ void scat_k(const int* __restrict__ adj, const int* __restrict__ ebi,
                       const int* __restrict__ offs, int* __restrict__ cur, int* __restrict__ esrc)
{
    int e = blockIdx.x * 256 + threadIdx.x;
    int bb = ebi[e];
    int d = bb * NN + adj[2 * e + 1];
    int s = bb * NN + adj[2 * e + 0];
    int pos = offs[d] + atomicAdd(&cur[d], 1);
    esrc[pos] = s;
}

// ===================== aggregation: agg[n] = sum_e relu(P1[src_e] + P2[n] + bm) ==============
__global__ void agg_k(const float* __restrict__ P1, const float* __restrict__ P2,
                      const float* __restrict__ bm, const int* __restrict__ offs,
                      const int* __restrict__ esrc, float* __restrict__ agg)
{
    int node = blockIdx.x * 4 + (threadIdx.x >> 6);
    int lane = threadIdx.x & 63;
    int beg = offs[node], end = offs[node + 1];
    float p2a = P2[(size_t)node * 128 + lane]      + bm[lane];
    float p2b = P2[(size_t)node * 128 + 64 + lane] + bm[64 + lane];
    float aa = 0.f, ab = 0.f;
    for (int i = beg; i < end; ++i) {
        int s = esrc[i];
        float va = P1[(size_t)s * 128 + lane]      + p2a;
        float vb = P1[(size_t)s * 128 + 64 + lane] + p2b;
        aa += fmaxf(va, 0.f);
        ab += fmaxf(vb, 0.f);
    }
    agg[(size_t)node * 128 + lane]      = aa;
    agg[(size_t)node * 128 + 64 + lane] = ab;
}

// ===================== generic fp32 GEMM: C = act(A1@B1 [+ A2@B2] + bias), N=128 =============
// M tiles of 128 rows; K in chunks of 64; B row-stride fixed 128.
__launch_bounds__(256, 2)
__global__ void gemm_k(const float* A1, int lda1, const float* B1, int nk1,
                       const float* A2, int lda2, const float* B2, int nk2,
                       const float* bias, float* C, int ldc,
                       int do_relu, const unsigned char* mask)
{
    __shared__ float As[128 * 64];   // col-group-XOR-swizzled
    __shared__ float Bs[64 * 128];
    const int tx  = threadIdx.x;
    const int rg  = tx >> 4;     // 0..15
    const int cg  = tx & 15;     // 0..15
    const int srg = rg & 3;
    const size_t row0 = (size_t)blockIdx.x * 128;

    float acc[8][8];
#pragma unroll
    for (int j = 0; j < 8; ++j)
#pragma unroll
        for (int i = 0; i < 8; ++i) acc[j][i] = 0.f;

    for (int part = 0; part < 2; ++part) {
        const float* A = part ? A2 : A1;
        const float* B = part ? B2 : B1;
        const int lda  = part ? lda2 : lda1;
        const int nk   = part ? nk2 : nk1;
        if (A == nullptr) break;
        for (int kb = 0; kb < nk; ++kb) {
            const int kc0 = kb * 64;
            __syncthreads();
#pragma unroll
            for (int t = 0; t < 8; ++t) {               // stage A chunk 128x64
                int idx = tx + t * 256;
                int r   = idx >> 4;
                int kq  = idx & 15;
                float4 v = *(const float4*)(A + (row0 + r) * lda + kc0 + kq * 4);
                int kqs = kq ^ (r & 3);
                *(float4*)(As + r * 64 + kqs * 4) = v;
            }
#pragma unroll
            for (int t = 0; t < 8; ++t) {               // stage B chunk 64x128
                int idx = tx + t * 256;
                int r   = idx >> 5;
                int cq  = idx & 31;
                *(float4*)(Bs + r * 128 + cq * 4) = *(const float4*)(B + (size_t)(kc0 + r) * 128 + cq * 4);
            }
            __syncthreads();
#pragma unroll 4
            for (int k4 = 0; k4 < 16; ++k4) {
                float4 a4[8];
#pragma unroll
                for (int j = 0; j < 8; ++j) {
                    int r = rg + 16 * j;
                    a4[j] = *(const float4*)(As + r * 64 + ((k4 ^ srg) << 2));
                }
#pragma unroll
                for (int w = 0; w < 4; ++w) {
                    float4 b0 = *(const float4*)(Bs + (k4 * 4 + w) * 128 + cg * 8);
                    float4 b1 = *(const float4*)(Bs + (k4 * 4 + w) * 128 + cg * 8 + 4);
#pragma unroll
                    for (int j = 0; j < 8; ++j) {
                        float a = (w == 0) ? a4[j].x : (w == 1) ? a4[j].y : (w == 2) ? a4[j].z : a4[j].w;
                        acc[j][0] += a * b0.x; acc[j][1] += a * b0.y;
                        acc[j][2] += a * b0.z; acc[j][3] += a * b0.w;
                        acc[j][4] += a * b1.x; acc[j][5] += a * b1.y;
                        acc[j][6] += a * b1.z; acc[j][7] += a * b1.w;
                    }
                }
            }
        }
    }

#pragma unroll
    for (int j = 0; j < 8; ++j) {
        size_t grow = row0 + rg + 16 * j;
        bool zero = (mask != nullptr) && mask[grow];
        float ov[8];
#pragma unroll
        for (int i = 0; i < 8; ++i) {
            float v = acc[j][i] + (bias ? bias[cg * 8 + i] : 0.f);
            if (do_relu) v = fmaxf(v, 0.f);
            if (zero) v = 0.f;
            ov[i] = v;
        }
        float* Crow = C + grow * ldc + cg * 8;
        float4 o0; o0.x = ov[0]; o0.y = ov[1]; o0.z = ov[2]; o0.w = ov[3];
        float4 o1; o1.x = ov[4]; o1.y = ov[5]; o1.z = ov[6]; o1.w = ov[7];
        *(float4*)(Crow)     = o0;
        *(float4*)(Crow + 4) = o1;
    }
}

// ===================== fill x cols 128..191 (cond, temps, zero pad) =====================
__global__ void xfill_k(const float* __restrict__ coords, const int* __restrict__ types,
                        const unsigned char* __restrict__ maskb, float* __restrict__ x)
{
    int node = blockIdx.x * 4 + (threadIdx.x >> 6);
    int i    = threadIdx.x & 63;
    int c    = 128 + i;
    bool valid = !maskb[node];
    bool coup  = (types[node] > 0) && valid;
    float v;
    if (c < 131)       v = coup ? 0.f : coords[(size_t)node * 3 + (c - 128)];
    else if (c == 131) v = 300.f;
    else if (c == 132) v = 600.f;
    else               v = 0.f;
    x[(size_t)node * 192 + c] = v;
}

// ===================== weight/bias padding =====================
__global__ void padW0_k(const float* __restrict__ W, float* __restrict__ Wp)  // 133x128 -> 192x128
{
    int idx = blockIdx.x * 256 + threadIdx.x;     // 192*128 = 24576
    int row = idx >> 7, col = idx & 127;
    Wp[idx] = (row < 133) ? W[row * 128 + col] : 0.f;
}
__global__ void padW2_k(const float* __restrict__ W, float* __restrict__ Wp)  // 128x64 -> 128x128
{
    int idx = blockIdx.x * 256 + threadIdx.x;     // 128*128 = 16384
    int row = idx >> 7, col = idx & 127;
    Wp[idx] = (col < 64) ? W[row * 64 + col] : 0.f;
}
__global__ void padb_k(const float* __restrict__ b, float* __restrict__ bp)   // 64 -> 128
{
    int c = threadIdx.x;
    bp[c] = (c < 64) ? b[c] : 0.f;
}

// ===================== layer-3 (64->3) x2 + coupling transform + logdet partials ============
__global__ void final_k(const float* __restrict__ t2s, const float* __restrict__ t2t,
                        const float* __restrict__ Ws3, const float* __restrict__ bs3,
                        const float* __restrict__ Wt3, const float* __restrict__ bt3,
                        const float* __restrict__ coords, const int* __restrict__ types,
                        const unsigned char* __restrict__ maskb,
                        float* __restrict__ outc, float* __restrict__ partial)
{
    int tx = threadIdx.x;
    int node = blockIdx.x * 256 + tx;
    float rs0 = bs3[0], rs1 = bs3[1], rs2 = bs3[2];
    float sh0 = bt3[0], sh1 = bt3[1], sh2 = bt3[2];
    const float* a = t2s + (size_t)node * 128;
    const float* b = t2t + (size_t)node * 128;
#pragma unroll 8
    for (int k = 0; k < 64; ++k) {
        float av = a[k], bv = b[k];
        rs0 += av * Ws3[k * 3 + 0]; rs1 += av * Ws3[k * 3 + 1]; rs2 += av * Ws3[k * 3 + 2];
        sh0 += bv * Wt3[k * 3 + 0]; sh1 += bv * Wt3[k * 3 + 1]; sh2 += bv * Wt3[k * 3 + 2];
    }
    bool valid = !maskb[node];
    bool coup  = (types[node] > 0) && valid;
    float c0 = coords[(size_t)node * 3 + 0];
    float c1 = coords[(size_t)node * 3 + 1];
    float c2 = coords[(size_t)node * 3 + 2];
    float ls0 = 0.f, ls1 = 0.f, ls2 = 0.f, o0 = c0, o1 = c1, o2 = c2;
    if (coup) {
        ls0 = tanhf(rs0) * 0.5f; ls1 = tanhf(rs1) * 0.5f; ls2 = tanhf(rs2) * 0.5f;
        o0 = expf(ls0) * c0 + sh0;
        o1 = expf(ls1) * c1 + sh1;
        o2 = expf(ls2) * c2 + sh2;
    }
    outc[(size_t)node * 3 + 0] = o0;
    outc[(size_t)node * 3 + 1] = o1;
    outc[(size_t)node * 3 + 2] = o2;
    __shared__ float red[256];
    red[tx] = ls0 + ls1 + ls2;
    __syncthreads();
    for (int s = 128; s > 0; s >>= 1) {
        if (tx < s) red[tx] += red[tx + s];
        __syncthreads();
    }
    if (tx == 0) partial[blockIdx.x] = red[0];
}

__global__ void red_k(const float* __restrict__ partial, float* __restrict__ ldet)
{
    __shared__ float s[256];
    int t = threadIdx.x;
    s[t] = partial[t];
    __syncthreads();
    if (t < 16) {
        float v = 0.f;
        for (int i = 0; i < 16; ++i) v += s[t * 16 + i];
        ldet[t] = v;   // each 256-node block lies fully inside one batch (4096 % 256 == 0)
    }
}

// ============================================================================================
extern "C" void kernel_launch(void* const* d_in, const int* in_sizes, int n_in,
                              void* d_out, int out_size, void* d_ws, size_t ws_size,
                              hipStream_t stream)
{
    (void)in_sizes; (void)n_in; (void)out_size; (void)ws_size;
    const float* coords = (const float*)d_in[0];
    const int*   types  = (const int*)d_in[1];
    const int*   adj    = (const int*)d_in[2];
    const int*   ebi    = (const int*)d_in[3];
    const unsigned char* maskb = (const unsigned char*)d_in[4];
    const float* embed  = (const float*)d_in[5];
    const float* W_in   = (const float*)d_in[6];
    const float* b_in   = (const float*)d_in[7];
    const float* W_msg[2] = {(const float*)d_in[8],  (const float*)d_in[12]};
    const float* b_msg[2] = {(const float*)d_in[9],  (const float*)d_in[13]};
    const float* W_upd[2] = {(const float*)d_in[10], (const float*)d_in[14]};
    const float* b_upd[2] = {(const float*)d_in[11], (const float*)d_in[15]};
    const float* W_out = (const float*)d_in[16]; const float* b_out = (const float*)d_in[17];
    const float* Ws0 = (const float*)d_in[18]; const float* bs0 = (const float*)d_in[19];
    const float* Ws1 = (const float*)d_in[20]; const float* bs1 = (const float*)d_in[21];
    const float* Ws2 = (const float*)d_in[22]; const float* bs2 = (const float*)d_in[23];
    const float* Ws3 = (const float*)d_in[24]; const float* bs3 = (const float*)d_in[25];
    const float* Wt0 = (const float*)d_in[26]; const float* bt0 = (const float*)d_in[27];
    const float* Wt1 = (const float*)d_in[28]; const float* bt1 = (const float*)d_in[29];
    const float* Wt2 = (const float*)d_in[30]; const float* bt2 = (const float*)d_in[31];
    const float* Wt3 = (const float*)d_in[32]; const float* bt3 = (const float*)d_in[33];

    char* ws = (char*)d_ws;
    size_t off = 0;
    auto alloc = [&](size_t bytes) { void* p = ws + off; off += (bytes + 255) & ~(size_t)255; return p; };
    float* hf   = (float*)alloc((size_t)NNODE * 128 * 4);
    float* agg  = (float*)alloc((size_t)NNODE * 128 * 4);
    float* P1   = (float*)alloc((size_t)NNODE * 128 * 4);
    float* P2   = (float*)alloc((size_t)NNODE * 128 * 4);
    float* x    = (float*)alloc((size_t)NNODE * 192 * 4);
    int*   deg  = (int*)alloc((size_t)NNODE * 4);
    int*   offs = (int*)alloc((size_t)(NNODE + 1) * 4);
    int*   cur  = (int*)alloc((size_t)NNODE * 4);
    int*   esrc = (int*)alloc((size_t)NE * 4);
    float* W0ps = (float*)alloc(192 * 128 * 4);
    float* W0pt = (float*)alloc(192 * 128 * 4);
    float* W2ps = (float*)alloc(128 * 128 * 4);
    float* W2pt = (float*)alloc(128 * 128 * 4);
    float* b2ps = (float*)alloc(128 * 4);
    float* b2pt = (float*)alloc(128 * 4);
    float* partial = (float*)alloc(256 * 4);

    hipMemsetAsync(deg, 0, (size_t)NNODE * 4, stream);
    hipMemsetAsync(cur, 0, (size_t)NNODE * 4, stream);

    init_k<<<NNODE / 2, 256, 0, stream>>>(types, coords, maskb, embed, W_in, b_in, hf);
    deg_k<<<NE / 256, 256, 0, stream>>>(adj, ebi, deg);
    scan_k<<<1, 1024, 0, stream>>>(deg, offs);
    scat_k<<<NE / 256, 256, 0, stream>>>(adj, ebi, offs, cur, esrc);

    padW0_k<<<(192 * 128) / 256, 256, 0, stream>>>(Ws0, W0ps);
    padW0_k<<<(192 * 128) / 256, 256, 0, stream>>>(Wt0, W0pt);
    padW2_k<<<(128 * 128) / 256, 256, 0, stream>>>(Ws2, W2ps);
    padW2_k<<<(128 * 128) / 256, 256, 0, stream>>>(Wt2, W2pt);
    padb_k<<<1, 128, 0, stream>>>(bs2, b2ps);
    padb_k<<<1, 128, 0, stream>>>(bt2, b2pt);

    for (int r = 0; r < 2; ++r) {
        gemm_k<<<512, 256, 0, stream>>>(hf, 128, W_msg[r], 2,
                                        nullptr, 0, nullptr, 0,
                                        nullptr, P1, 128, 0, nullptr);
        gemm_k<<<512, 256, 0, stream>>>(hf, 128, W_msg[r] + 128 * 128, 2,
                                        nullptr, 0, nullptr, 0,
                                        nullptr, P2, 128, 0, nullptr);
        agg_k<<<NNODE / 4, 256, 0, stream>>>(P1, P2, b_msg[r], offs, esrc, agg);
        gemm_k<<<512, 256, 0, stream>>>(hf, 128, W_upd[r], 2,
                                        agg, 128, W_upd[r] + 128 * 128, 2,
                                        b_upd[r], hf, 128, 1, nullptr);
    }

    // node_feats written into x cols 0..127 (masked rows zeroed)
    gemm_k<<<512, 256, 0, stream>>>(hf, 128, W_out, 2,
                                    nullptr, 0, nullptr, 0,
                                    b_out, x, 192, 0, maskb);
    xfill_k<<<NNODE / 4, 256, 0, stream>>>(coords, types, maskb, x);

    // scale MLP: x -> P1 -> P2 -> agg
    gemm_k<<<512, 256, 0, stream>>>(x, 192, W0ps, 3, nullptr, 0, nullptr, 0, bs0, P1, 128, 1, nullptr);
    gemm_k<<<512, 256, 0, stream>>>(P1, 128, Ws1, 2, nullptr, 0, nullptr, 0, bs1, P2, 128, 1, nullptr);
    gemm_k<<<512, 256, 0, stream>>>(P2, 128, W2ps, 2, nullptr, 0, nullptr, 0, b2ps, agg, 128, 1, nullptr);
    // shift MLP: x -> P1 -> P2 -> hf
    gemm_k<<<512, 256, 0, stream>>>(x, 192, W0pt, 3, nullptr, 0, nullptr, 0, bt0, P1, 128, 1, nullptr);
    gemm_k<<<512, 256, 0, stream>>>(P1, 128, Wt1, 2, nullptr, 0, nullptr, 0, bt1, P2, 128, 1, nullptr);
    gemm_k<<<512, 256, 0, stream>>>(P2, 128, W2pt, 2, nullptr, 0, nullptr, 0, b2pt, hf, 128, 1, nullptr);

    float* outc = (float*)d_out;
    final_k<<<NNODE / 256, 256, 0, stream>>>(agg, hf, Ws3, bs3, Wt3, bt3,
                                             coords, types, maskb, outc, partial);
    red_k<<<1, 256, 0, stream>>>(partial, outc + (size_t)NNODE * 3);
}

// Round 2
// 579.131 us; speedup vs baseline: 1.3962x; 1.3962x over previous
//
#include <hip/hip_runtime.h>

#define NB    16
#define NN    4096
#define NNODE (NB*NN)   // 65536
#define NE    524288

typedef __attribute__((ext_vector_type(8))) short bf16x8_t;
typedef __attribute__((ext_vector_type(4))) float f32x4_t;

__device__ __forceinline__ unsigned short f2bf(float f) {
    union { float f; unsigned u; } v; v.f = f;
    return (unsigned short)((v.u + 0x7FFFu + ((v.u >> 16) & 1u)) >> 16);  // RNE
}
__device__ __forceinline__ float bf2f(unsigned short h) {
    union { unsigned u; float f; } v; v.u = ((unsigned)h) << 16;
    return v.f;
}

// ===================== init: h0 = relu([embed|coords] @ W_in + b_in) * vf  -> bf16 ==========
__global__ void init_k(const int* __restrict__ types, const float* __restrict__ coords,
                       const unsigned char* __restrict__ maskb,
                       const float* __restrict__ embed, const float* __restrict__ W_in,
                       const float* __restrict__ b_in, unsigned short* __restrict__ hf)
{
    int half = threadIdx.x >> 7;
    int c    = threadIdx.x & 127;
    int node = blockIdx.x * 2 + half;
    __shared__ float xs[2][8];
    if (c < 4)      xs[half][c] = embed[(size_t)types[node] * 4 + c];
    else if (c < 7) xs[half][c] = coords[(size_t)node * 3 + (c - 4)];
    __syncthreads();
    float acc = b_in[c];
#pragma unroll
    for (int k = 0; k < 7; ++k) acc += xs[half][k] * W_in[k * 128 + c];
    hf[(size_t)node * 128 + c] = maskb[node] ? (unsigned short)0 : f2bf(fmaxf(acc, 0.f));
}

// ===================== CSR build (by dst) =====================
__global__ void deg_k(const int* __restrict__ adj, const int* __restrict__ ebi, int* __restrict__ deg)
{
    int e = blockIdx.x * 256 + threadIdx.x;
    atomicAdd(&deg[ebi[e] * NN + adj[2 * e + 1]], 1);
}

__global__ void scan_k(const int* __restrict__ deg, int* __restrict__ offs)
{
    __shared__ int sums[1024];
    int t = threadIdx.x;
    int base = t * 64;
    int s = 0;
    for (int i = 0; i < 64; ++i) s += deg[base + i];
    sums[t] = s;
    __syncthreads();
    for (int off = 1; off < 1024; off <<= 1) {
        int add = (t >= off) ? sums[t - off] : 0;
        __syncthreads();
        sums[t] += add;
        __syncthreads();
    }
    int run = (t > 0) ? sums[t - 1] : 0;
    for (int i = 0; i < 64; ++i) { offs[base + i] = run; run += deg[base + i]; }
    if (t == 1023) offs[NNODE] = run;
}

__global__ void scat_k(const int* __restrict__ adj, const int* __restrict__ ebi,
                       const int* __restrict__ offs, int* __restrict__ cur, int* __restrict__ esrc)
{
    int e = blockIdx.x * 256 + threadIdx.x;
    int bb = ebi[e];
    int d = bb * NN + adj[2 * e + 1];
    int s = bb * NN + adj[2 * e + 0];
    esrc[offs[d] + atomicAdd(&cur[d], 1)] = s;
}

// ===================== weight prep: Bt[n][k] = W[k][n]  (bf16, padded) =====================
__global__ void prep_k(const float* __restrict__ Wm0, const float* __restrict__ Wm1,
                       const float* __restrict__ Wu0, const float* __restrict__ Wu1,
                       const float* __restrict__ Wout,
                       const float* __restrict__ Ws0, const float* __restrict__ Wt0,
                       const float* __restrict__ Ws1, const float* __restrict__ Wt1,
                       const float* __restrict__ Ws2, const float* __restrict__ Wt2,
                       const float* __restrict__ bs2, const float* __restrict__ bt2,
                       unsigned short* __restrict__ Btm0, unsigned short* __restrict__ Btm1,
                       unsigned short* __restrict__ Btu0, unsigned short* __restrict__ Btu1,
                       unsigned short* __restrict__ Btout,
                       unsigned short* __restrict__ Bts0, unsigned short* __restrict__ Btt0,
                       unsigned short* __restrict__ Bts1, unsigned short* __restrict__ Btt1,
                       unsigned short* __restrict__ Bts2, unsigned short* __restrict__ Btt2,
                       float* __restrict__ b2ps, float* __restrict__ b2pt)
{
    int bid = blockIdx.x, tx = threadIdx.x;
    if (bid < 256) {            // msg: Bt [256][128]; n<128 -> Wm[k][n], n>=128 -> Wm[128+k][n-128]
        const float* W = bid < 128 ? Wm0 : Wm1;
        unsigned short* Bt = bid < 128 ? Btm0 : Btm1;
        int idx = (bid & 127) * 256 + tx;
        int n = idx >> 7, k = idx & 127;
        float v = (n < 128) ? W[k * 128 + n] : W[(128 + k) * 128 + (n - 128)];
        Bt[n * 128 + k] = f2bf(v);
    } else if (bid < 512) {     // upd: Bt [128][256] = full transpose of (256x128)
        const float* W = bid < 384 ? Wu0 : Wu1;
        unsigned short* Bt = bid < 384 ? Btu0 : Btu1;
        int idx = ((bid - 256) & 127) * 256 + tx;
        int n = idx >> 8, k = idx & 255;
        Bt[n * 256 + k] = f2bf(W[k * 128 + n]);
    } else if (bid < 576) {     // W_out [128][128]
        int idx = (bid - 512) * 256 + tx;
        int n = idx >> 7, k = idx & 127;
        Btout[n * 128 + k] = f2bf(Wout[k * 128 + n]);
    } else if (bid < 768) {     // L0: [128][192], k<133 real
        const float* W = bid < 672 ? Ws0 : Wt0;
        unsigned short* Bt = bid < 672 ? Bts0 : Btt0;
        int idx = ((bid - 576) % 96) * 256 + tx;
        int n = idx / 192, kk = idx % 192;
        Bt[n * 192 + kk] = f2bf(kk < 133 ? W[kk * 128 + n] : 0.f);
    } else if (bid < 896) {     // L1 [128][128]
        const float* W = bid < 832 ? Ws1 : Wt1;
        unsigned short* Bt = bid < 832 ? Bts1 : Btt1;
        int idx = ((bid - 768) & 63) * 256 + tx;
        int n = idx >> 7, k = idx & 127;
        Bt[n * 128 + k] = f2bf(W[k * 128 + n]);
    } else if (bid < 1024) {    // L2: [128][128], n<64 real (W is 128x64)
        const float* W = bid < 960 ? Ws2 : Wt2;
        unsigned short* Bt = bid < 960 ? Bts2 : Btt2;
        int idx = ((bid - 896) & 63) * 256 + tx;
        int n = idx >> 7, k = idx & 127;
        Bt[n * 128 + k] = f2bf(n < 64 ? W[k * 64 + n] : 0.f);
    } else {                    // padded biases for L2
        if (tx < 128) b2ps[tx] = (tx < 64) ? bs2[tx] : 0.f;
        else { int c = tx - 128; b2pt[c] = (c < 64) ? bt2[c] : 0.f; }
    }
}

// ===================== bf16 MFMA GEMM: C = act(A1@Bt^T [|A2 cont.] + bias) =====================
// 128x128 C-tile per block, 4 waves in 2x2 (64x64 each), K chunks of 64, XOR-swizzled LDS.
__launch_bounds__(256, 2)
__global__ void mgemm_k(const unsigned short* A1, int lda1, int K1,
                        const unsigned short* A2, int lda2, int K2,
                        const unsigned short* __restrict__ Bt, int ldbt,
                        const float* __restrict__ bias, int do_relu,
                        const unsigned char* __restrict__ mask,
                        unsigned short* C, int ldc)
{
    __shared__ __align__(16) unsigned short As[128 * 64];
    __shared__ __align__(16) unsigned short Bs[128 * 64];
    const int tx = threadIdx.x;
    const int w  = tx >> 6;
    const int l  = tx & 63;
    const size_t row0 = (size_t)blockIdx.x * 128;
    const int colb = blockIdx.y * 128;
    const unsigned short* BtB = Bt + (size_t)colb * ldbt;

    f32x4_t acc[4][4];
#pragma unroll
    for (int i = 0; i < 4; ++i)
#pragma unroll
        for (int j = 0; j < 4; ++j) { f32x4_t z = {0.f, 0.f, 0.f, 0.f}; acc[i][j] = z; }

    const int rA  = l >> 3;      // 0..7 row-in-group
    const int kgA = l & 7;       // 16B k-group
    const int Ktot = K1 + K2;

    for (int kc = 0; kc < Ktot; kc += 64) {
        const unsigned short* Ap; int lda, kloc;
        if (kc < K1) { Ap = A1; lda = lda1; kloc = kc; }
        else         { Ap = A2; lda = lda2; kloc = kc - K1; }
        uint4 va[4], vb[4];
#pragma unroll
        for (int i = 0; i < 4; ++i) {
            int r = w * 32 + i * 8 + rA;
            va[i] = *(const uint4*)(Ap + (row0 + r) * lda + kloc + kgA * 8);
            vb[i] = *(const uint4*)(BtB + (size_t)r * ldbt + kc + kgA * 8);
        }
        __syncthreads();   // previous-iter LDS reads done
#pragma unroll
        for (int i = 0; i < 4; ++i) {
            int r = w * 32 + i * 8 + rA;
            int swz = ((kgA ^ (r & 7)) << 4);          // XOR-swizzled byte-in-row
            *(uint4*)((char*)As + r * 128 + swz) = va[i];
            *(uint4*)((char*)Bs + r * 128 + swz) = vb[i];
        }
        __syncthreads();
        const int rsel = l & 15;
        const int kq   = l >> 4;
#pragma unroll
        for (int ks = 0; ks < 2; ++ks) {
            bf16x8_t af[4], bv[4];
#pragma unroll
            for (int fm = 0; fm < 4; ++fm) {
                int r = ((w >> 1) * 64) + fm * 16 + rsel;
                int byte = r * 128 + ((ks * 64 + kq * 16) ^ ((r & 7) << 4));
                af[fm] = *(const bf16x8_t*)((const char*)As + byte);
            }
#pragma unroll
            for (int fn = 0; fn < 4; ++fn) {
                int r = ((w & 1) * 64) + fn * 16 + rsel;
                int byte = r * 128 + ((ks * 64 + kq * 16) ^ ((r & 7) << 4));
                bv[fn] = *(const bf16x8_t*)((const char*)Bs + byte);
            }
#pragma unroll
            for (int fm = 0; fm < 4; ++fm)
#pragma unroll
                for (int fn = 0; fn < 4; ++fn)
                    acc[fm][fn] = __builtin_amdgcn_mfma_f32_16x16x32_bf16(af[fm], bv[fn], acc[fm][fn], 0, 0, 0);
        }
    }

    // epilogue: D frag mapping col=l&15, row=(l>>4)*4+reg
    const int rg = l >> 4;
    const int cc = l & 15;
#pragma unroll
    for (int fm = 0; fm < 4; ++fm) {
#pragma unroll
        for (int r = 0; r < 4; ++r) {
            size_t grow = row0 + (size_t)((w >> 1) * 64 + fm * 16 + rg * 4 + r);
            bool zero = (mask != nullptr) && mask[grow];
#pragma unroll
            for (int fn = 0; fn < 4; ++fn) {
                int gcol = colb + (w & 1) * 64 + fn * 16 + cc;
                float v = acc[fm][fn][r] + (bias ? bias[gcol] : 0.f);
                if (do_relu) v = fmaxf(v, 0.f);
                if (zero) v = 0.f;
                C[grow * ldc + gcol] = f2bf(v);
            }
        }
    }
}

// ===================== aggregation: agg[n] = sum_e relu(P1[src_e] + P2[n] + bm)  (bf16) ======
__global__ void agg_k(const unsigned short* __restrict__ P12, const float* __restrict__ bm,
                      const int* __restrict__ offs, const int* __restrict__ esrc,
                      unsigned short* __restrict__ agg)
{
    int node = blockIdx.x * 4 + (threadIdx.x >> 6);
    int l = threadIdx.x & 63;
    int beg = offs[node], end = offs[node + 1];
    unsigned p2w = *(const unsigned*)(P12 + (size_t)node * 256 + 128 + 2 * l);
    float p2a = bf2f((unsigned short)(p2w & 0xFFFF))  + bm[2 * l];
    float p2b = bf2f((unsigned short)(p2w >> 16))     + bm[2 * l + 1];
    float aa = 0.f, ab = 0.f;
    for (int i = beg; i < end; ++i) {
        int s = esrc[i];
        unsigned v = *(const unsigned*)(P12 + (size_t)s * 256 + 2 * l);
        aa += fmaxf(bf2f((unsigned short)(v & 0xFFFF)) + p2a, 0.f);
        ab += fmaxf(bf2f((unsigned short)(v >> 16))    + p2b, 0.f);
    }
    unsigned o = (unsigned)f2bf(aa) | ((unsigned)f2bf(ab) << 16);
    *(unsigned*)(agg + (size_t)node * 128 + 2 * l) = o;
}

// ===================== fill x cols 128..191 (cond, temps, pad) bf16 =====================
__global__ void xfill_k(const float* __restrict__ coords, const int* __restrict__ types,
                        const unsigned char* __restrict__ maskb, unsigned short* __restrict__ x)
{
    int node = blockIdx.x * 4 + (threadIdx.x >> 6);
    int i    = threadIdx.x & 63;
    int c    = 128 + i;
    bool valid = !maskb[node];
    bool coup  = (types[node] > 0) && valid;
    float v;
    if (c < 131)       v = coup ? 0.f : coords[(size_t)node * 3 + (c - 128)];
    else if (c == 131) v = 300.f;
    else if (c == 132) v = 600.f;
    else               v = 0.f;
    x[(size_t)node * 192 + c] = f2bf(v);
}

// ===================== layer-3 (64->3) x2 + coupling transform + logdet partials ============
__global__ void final_k(const unsigned short* __restrict__ t2s, const unsigned short* __restrict__ t2t,
                        const float* __restrict__ Ws3, const float* __restrict__ bs3,
                        const float* __restrict__ Wt3, const float* __restrict__ bt3,
                        const float* __restrict__ coords, const int* __restrict__ types,
                        const unsigned char* __restrict__ maskb,
                        float* __restrict__ outc, float* __restrict__ partial)
{
    int tx = threadIdx.x;
    int node = blockIdx.x * 256 + tx;
    float rs0 = bs3[0], rs1 = bs3[1], rs2 = bs3[2];
    float sh0 = bt3[0], sh1 = bt3[1], sh2 = bt3[2];
    const unsigned short* a = t2s + (size_t)node * 128;
    const unsigned short* b = t2t + (size_t)node * 128;
#pragma unroll 8
    for (int k = 0; k < 64; ++k) {
        float av = bf2f(a[k]), bv = bf2f(b[k]);
        rs0 += av * Ws3[k * 3 + 0]; rs1 += av * Ws3[k * 3 + 1]; rs2 += av * Ws3[k * 3 + 2];
        sh0 += bv * Wt3[k * 3 + 0]; sh1 += bv * Wt3[k * 3 + 1]; sh2 += bv * Wt3[k * 3 + 2];
    }
    bool valid = !maskb[node];
    bool coup  = (types[node] > 0) && valid;
    float c0 = coords[(size_t)node * 3 + 0];
    float c1 = coords[(size_t)node * 3 + 1];
    float c2 = coords[(size_t)node * 3 + 2];
    float ls0 = 0.f, ls1 = 0.f, ls2 = 0.f, o0 = c0, o1 = c1, o2 = c2;
    if (coup) {
        ls0 = tanhf(rs0) * 0.5f; ls1 = tanhf(rs1) * 0.5f; ls2 = tanhf(rs2) * 0.5f;
        o0 = expf(ls0) * c0 + sh0;
        o1 = expf(ls1) * c1 + sh1;
        o2 = expf(ls2) * c2 + sh2;
    }
    outc[(size_t)node * 3 + 0] = o0;
    outc[(size_t)node * 3 + 1] = o1;
    outc[(size_t)node * 3 + 2] = o2;
    __shared__ float red[256];
    red[tx] = ls0 + ls1 + ls2;
    __syncthreads();
    for (int s = 128; s > 0; s >>= 1) {
        if (tx < s) red[tx] += red[tx + s];
        __syncthreads();
    }
    if (tx == 0) partial[blockIdx.x] = red[0];
}

__global__ void red_k(const float* __restrict__ partial, float* __restrict__ ldet)
{
    __shared__ float s[256];
    int t = threadIdx.x;
    s[t] = partial[t];
    __syncthreads();
    if (t < 16) {
        float v = 0.f;
        for (int i = 0; i < 16; ++i) v += s[t * 16 + i];
        ldet[t] = v;
    }
}

// ============================================================================================
extern "C" void kernel_launch(void* const* d_in, const int* in_sizes, int n_in,
                              void* d_out, int out_size, void* d_ws, size_t ws_size,
                              hipStream_t stream)
{
    (void)in_sizes; (void)n_in; (void)out_size; (void)ws_size;
    const float* coords = (const float*)d_in[0];
    const int*   types  = (const int*)d_in[1];
    const int*   adj    = (const int*)d_in[2];
    const int*   ebi    = (const int*)d_in[3];
    const unsigned char* maskb = (const unsigned char*)d_in[4];
    const float* embed  = (const float*)d_in[5];
    const float* W_in   = (const float*)d_in[6];
    const float* b_in   = (const float*)d_in[7];
    const float* W_msg[2] = {(const float*)d_in[8],  (const float*)d_in[12]};
    const float* b_msg[2] = {(const float*)d_in[9],  (const float*)d_in[13]};
    const float* W_upd[2] = {(const float*)d_in[10], (const float*)d_in[14]};
    const float* b_upd[2] = {(const float*)d_in[11], (const float*)d_in[15]};
    const float* W_out = (const float*)d_in[16]; const float* b_out = (const float*)d_in[17];
    const float* Ws0 = (const float*)d_in[18]; const float* bs0 = (const float*)d_in[19];
    const float* Ws1 = (const float*)d_in[20]; const float* bs1 = (const float*)d_in[21];
    const float* Ws2 = (const float*)d_in[22]; const float* bs2 = (const float*)d_in[23];
    const float* Ws3 = (const float*)d_in[24]; const float* bs3 = (const float*)d_in[25];
    const float* Wt0 = (const float*)d_in[26]; const float* bt0 = (const float*)d_in[27];
    const float* Wt1 = (const float*)d_in[28]; const float* bt1 = (const float*)d_in[29];
    const float* Wt2 = (const float*)d_in[30]; const float* bt2 = (const float*)d_in[31];
    const float* Wt3 = (const float*)d_in[32]; const float* bt3 = (const float*)d_in[33];

    char* ws = (char*)d_ws;
    size_t off = 0;
    auto alloc = [&](size_t bytes) { void* p = ws + off; off += (bytes + 255) & ~(size_t)255; return p; };
    unsigned short* hf   = (unsigned short*)alloc((size_t)NNODE * 128 * 2);   // also h1
    unsigned short* P12  = (unsigned short*)alloc((size_t)NNODE * 256 * 2);   // also h2t (first half)
    unsigned short* agg  = (unsigned short*)alloc((size_t)NNODE * 128 * 2);   // also h2s
    unsigned short* x    = (unsigned short*)alloc((size_t)NNODE * 192 * 2);
    int*   deg  = (int*)alloc((size_t)NNODE * 4);
    int*   offs = (int*)alloc((size_t)(NNODE + 1) * 4);
    int*   cur  = (int*)alloc((size_t)NNODE * 4);
    int*   esrc = (int*)alloc((size_t)NE * 4);
    unsigned short* Btm0 = (unsigned short*)alloc(256 * 128 * 2);
    unsigned short* Btm1 = (unsigned short*)alloc(256 * 128 * 2);
    unsigned short* Btu0 = (unsigned short*)alloc(128 * 256 * 2);
    unsigned short* Btu1 = (unsigned short*)alloc(128 * 256 * 2);
    unsigned short* Btout= (unsigned short*)alloc(128 * 128 * 2);
    unsigned short* Bts0 = (unsigned short*)alloc(128 * 192 * 2);
    unsigned short* Btt0 = (unsigned short*)alloc(128 * 192 * 2);
    unsigned short* Bts1 = (unsigned short*)alloc(128 * 128 * 2);
    unsigned short* Btt1 = (unsigned short*)alloc(128 * 128 * 2);
    unsigned short* Bts2 = (unsigned short*)alloc(128 * 128 * 2);
    unsigned short* Btt2 = (unsigned short*)alloc(128 * 128 * 2);
    float* b2ps = (float*)alloc(128 * 4);
    float* b2pt = (float*)alloc(128 * 4);
    float* partial = (float*)alloc(256 * 4);

    hipMemsetAsync(deg, 0, (size_t)NNODE * 4, stream);
    hipMemsetAsync(cur, 0, (size_t)NNODE * 4, stream);

    init_k<<<NNODE / 2, 256, 0, stream>>>(types, coords, maskb, embed, W_in, b_in, hf);
    deg_k<<<NE / 256, 256, 0, stream>>>(adj, ebi, deg);
    scan_k<<<1, 1024, 0, stream>>>(deg, offs);
    scat_k<<<NE / 256, 256, 0, stream>>>(adj, ebi, offs, cur, esrc);
    prep_k<<<1025, 256, 0, stream>>>(W_msg[0], W_msg[1], W_upd[0], W_upd[1], W_out,
                                     Ws0, Wt0, Ws1, Wt1, Ws2, Wt2, bs2, bt2,
                                     Btm0, Btm1, Btu0, Btu1, Btout,
                                     Bts0, Btt0, Bts1, Btt1, Bts2, Btt2, b2ps, b2pt);

    const unsigned short* Btm[2] = {Btm0, Btm1};
    const unsigned short* Btu[2] = {Btu0, Btu1};
    for (int r = 0; r < 2; ++r) {
        mgemm_k<<<dim3(512, 2), 256, 0, stream>>>(hf, 128, 128, nullptr, 0, 0,
                                                  Btm[r], 128, nullptr, 0, nullptr, P12, 256);
        agg_k<<<NNODE / 4, 256, 0, stream>>>(P12, b_msg[r], offs, esrc, agg);
        mgemm_k<<<dim3(512, 1), 256, 0, stream>>>(hf, 128, 128, agg, 128, 128,
                                                  Btu[r], 256, b_upd[r], 1, nullptr, hf, 128);
    }

    // node_feats -> x cols 0..127 (masked rows zeroed), then cond/temps/pad
    mgemm_k<<<dim3(512, 1), 256, 0, stream>>>(hf, 128, 128, nullptr, 0, 0,
                                              Btout, 128, b_out, 0, maskb, x, 192);
    xfill_k<<<NNODE / 4, 256, 0, stream>>>(coords, types, maskb, x);

    // scale MLP: x -> h1(hf) -> h1 -> h2s(agg)
    mgemm_k<<<dim3(512, 1), 256, 0, stream>>>(x, 192, 192, nullptr, 0, 0, Bts0, 192, bs0, 1, nullptr, hf, 128);
    mgemm_k<<<dim3(512, 1), 256, 0, stream>>>(hf, 128, 128, nullptr, 0, 0, Bts1, 128, bs1, 1, nullptr, hf, 128);
    mgemm_k<<<dim3(512, 1), 256, 0, stream>>>(hf, 128, 128, nullptr, 0, 0, Bts2, 128, b2ps, 1, nullptr, agg, 128);
    // shift MLP: x -> h1(hf) -> h1 -> h2t(P12)
    mgemm_k<<<dim3(512, 1), 256, 0, stream>>>(x, 192, 192, nullptr, 0, 0, Btt0, 192, bt0, 1, nullptr, hf, 128);
    mgemm_k<<<dim3(512, 1), 256, 0, stream>>>(hf, 128, 128, nullptr, 0, 0, Btt1, 128, bt1, 1, nullptr, hf, 128);
    mgemm_k<<<dim3(512, 1), 256, 0, stream>>>(hf, 128, 128, nullptr, 0, 0, Btt2, 128, b2pt, 1, nullptr, P12, 128);

    float* outc = (float*)d_out;
    final_k<<<NNODE / 256, 256, 0, stream>>>(agg, P12, Ws3, bs3, Wt3, bt3,
                                             coords, types, maskb, outc, partial);
    red_k<<<1, 256, 0, stream>>>(partial, outc + (size_t)NNODE * 3);
}

// Round 3
// 488.958 us; speedup vs baseline: 1.6537x; 1.1844x over previous
//
#include <hip/hip_runtime.h>

#define NB    16
#define NN    4096
#define NNODE (NB*NN)   // 65536
#define NE    524288

typedef __attribute__((ext_vector_type(8))) short bf16x8_t;
typedef __attribute__((ext_vector_type(4))) float f32x4_t;

__device__ __forceinline__ unsigned short f2bf(float f) {
    union { float f; unsigned u; } v; v.f = f;
    return (unsigned short)((v.u + 0x7FFFu + ((v.u >> 16) & 1u)) >> 16);  // RNE
}
__device__ __forceinline__ float bf2f(unsigned short h) {
    union { unsigned u; float f; } v; v.u = ((unsigned)h) << 16;
    return v.f;
}

// ===================== init: h0 = relu([embed|coords] @ W_in + b_in) * vf  -> bf16 ==========
__global__ void init_k(const int* __restrict__ types, const float* __restrict__ coords,
                       const unsigned char* __restrict__ maskb,
                       const float* __restrict__ embed, const float* __restrict__ W_in,
                       const float* __restrict__ b_in, unsigned short* __restrict__ hf)
{
    int half = threadIdx.x >> 7;
    int c    = threadIdx.x & 127;
    int node = blockIdx.x * 2 + half;
    __shared__ float xs[2][8];
    if (c < 4)      xs[half][c] = embed[(size_t)types[node] * 4 + c];
    else if (c < 7) xs[half][c] = coords[(size_t)node * 3 + (c - 4)];
    __syncthreads();
    float acc = b_in[c];
#pragma unroll
    for (int k = 0; k < 7; ++k) acc += xs[half][k] * W_in[k * 128 + c];
    hf[(size_t)node * 128 + c] = maskb[node] ? (unsigned short)0 : f2bf(fmaxf(acc, 0.f));
}

// ===================== CSR build (by dst) =====================
__global__ void deg_k(const int* __restrict__ adj, const int* __restrict__ ebi, int* __restrict__ deg)
{
    int e = blockIdx.x * 256 + threadIdx.x;
    atomicAdd(&deg[ebi[e] * NN + adj[2 * e + 1]], 1);
}

__global__ void scan_k(const int* __restrict__ deg, int* __restrict__ offs)
{
    __shared__ int sums[1024];
    int t = threadIdx.x;
    int base = t * 64;
    int s = 0;
    for (int i = 0; i < 64; ++i) s += deg[base + i];
    sums[t] = s;
    __syncthreads();
    for (int off = 1; off < 1024; off <<= 1) {
        int add = (t >= off) ? sums[t - off] : 0;
        __syncthreads();
        sums[t] += add;
        __syncthreads();
    }
    int run = (t > 0) ? sums[t - 1] : 0;
    for (int i = 0; i < 64; ++i) { offs[base + i] = run; run += deg[base + i]; }
    if (t == 1023) offs[NNODE] = run;
}

__global__ void scat_k(const int* __restrict__ adj, const int* __restrict__ ebi,
                       const int* __restrict__ offs, int* __restrict__ cur, int* __restrict__ esrc)
{
    int e = blockIdx.x * 256 + threadIdx.x;
    int bb = ebi[e];
    int d = bb * NN + adj[2 * e + 1];
    int s = bb * NN + adj[2 * e + 0];
    esrc[offs[d] + atomicAdd(&cur[d], 1)] = s;
}

// ===================== weight prep: Bt[n][k] = W[k][n]  (bf16, padded/concatenated) =========
__global__ void prep_k(const float* __restrict__ Wm0, const float* __restrict__ Wm1,
                       const float* __restrict__ Wu0, const float* __restrict__ Wu1,
                       const float* __restrict__ Wout,
                       const float* __restrict__ Ws0, const float* __restrict__ Wt0,
                       const float* __restrict__ Ws1, const float* __restrict__ Wt1,
                       const float* __restrict__ Ws2, const float* __restrict__ Wt2,
                       const float* __restrict__ bs0, const float* __restrict__ bt0,
                       const float* __restrict__ bs1, const float* __restrict__ bt1,
                       const float* __restrict__ bs2, const float* __restrict__ bt2,
                       const float* __restrict__ bm0, const float* __restrict__ bm1,
                       unsigned short* __restrict__ Btm0, unsigned short* __restrict__ Btm1,
                       unsigned short* __restrict__ Btu0, unsigned short* __restrict__ Btu1,
                       unsigned short* __restrict__ Btout,
                       unsigned short* __restrict__ Bt0cat, unsigned short* __restrict__ Bt1cat,
                       unsigned short* __restrict__ Bt2cat,
                       float* __restrict__ b0cat, float* __restrict__ b1cat,
                       float* __restrict__ b2cat,
                       float* __restrict__ bm0cat, float* __restrict__ bm1cat)
{
    int bid = blockIdx.x, tx = threadIdx.x;
    if (bid < 256) {            // msg: Bt [256][128]; n<128 -> Wm[k][n], n>=128 -> Wm[128+k][n-128]
        const float* W = bid < 128 ? Wm0 : Wm1;
        unsigned short* Bt = bid < 128 ? Btm0 : Btm1;
        int idx = (bid & 127) * 256 + tx;
        int n = idx >> 7, k = idx & 127;
        float v = (n < 128) ? W[k * 128 + n] : W[(128 + k) * 128 + (n - 128)];
        Bt[n * 128 + k] = f2bf(v);
    } else if (bid < 512) {     // upd: Bt [128][256] = transpose of (256x128)
        const float* W = bid < 384 ? Wu0 : Wu1;
        unsigned short* Bt = bid < 384 ? Btu0 : Btu1;
        int idx = ((bid - 256) & 127) * 256 + tx;
        int n = idx >> 8, k = idx & 255;
        Bt[n * 256 + k] = f2bf(W[k * 128 + n]);
    } else if (bid < 576) {     // W_out [128][128]
        int idx = (bid - 512) * 256 + tx;
        int n = idx >> 7, k = idx & 127;
        Btout[n * 128 + k] = f2bf(Wout[k * 128 + n]);
    } else if (bid < 768) {     // L0 cat: [256][192], k<133 real; n<128 scale, else shift
        int idx = (bid - 576) * 256 + tx;
        int n = idx / 192, kk = idx % 192;
        const float* W = n < 128 ? Ws0 : Wt0;
        int nn = n & 127;
        Bt0cat[n * 192 + kk] = f2bf(kk < 133 ? W[kk * 128 + nn] : 0.f);
    } else if (bid < 896) {     // L1 cat: [256][128]
        int idx = (bid - 768) * 256 + tx;
        int n = idx >> 7, k = idx & 127;
        const float* W = n < 128 ? Ws1 : Wt1;
        Bt1cat[n * 128 + k] = f2bf(W[k * 128 + (n & 127)]);
    } else if (bid < 1024) {    // L2 cat: [256][128], real n in [0,64) and [128,192)
        int idx = (bid - 896) * 256 + tx;
        int n = idx >> 7, k = idx & 127;
        const float* W = n < 128 ? Ws2 : Wt2;
        int nn = n & 127;
        Bt2cat[n * 128 + k] = f2bf(nn < 64 ? W[k * 64 + nn] : 0.f);
    } else if (bid == 1024) {
        b0cat[tx] = (tx < 128) ? bs0[tx] : bt0[tx - 128];
    } else if (bid == 1025) {
        b1cat[tx] = (tx < 128) ? bs1[tx] : bt1[tx - 128];
    } else if (bid == 1026) {
        int nn = tx & 127;
        b2cat[tx] = (nn < 64) ? ((tx < 128) ? bs2[nn] : bt2[nn]) : 0.f;
    } else if (bid == 1027) {
        bm0cat[tx] = (tx < 128) ? 0.f : bm0[tx - 128];
    } else {
        bm1cat[tx] = (tx < 128) ? 0.f : bm1[tx - 128];
    }
}

// ===================== bf16 MFMA GEMM, LDS-staged coalesced epilogue =====================
// 128x128 C-tile per block, 4 waves 2x2 (64x64 each), K chunks of 64, XOR-swizzled LDS.
__launch_bounds__(256, 2)
__global__ void mgemm_k(const unsigned short* A1, int lda1, int K1,
                        const unsigned short* A2, int lda2, int K2,
                        int aYStride,
                        const unsigned short* __restrict__ Bt, int ldbt,
                        const float* __restrict__ bias, int do_relu,
                        const unsigned char* __restrict__ mask,
                        unsigned short* C, int ldc)
{
    __shared__ __align__(16) char smem[32768];
    unsigned short* As = (unsigned short*)smem;
    unsigned short* Bs = (unsigned short*)(smem + 16384);
    const int tx = threadIdx.x;
    const int w  = tx >> 6;
    const int l  = tx & 63;
    const size_t row0 = (size_t)blockIdx.x * 128;
    const int colb = blockIdx.y * 128;
    const unsigned short* BtB = Bt + (size_t)colb * ldbt;
    A1 += (size_t)blockIdx.y * aYStride;
    if (A2) A2 += (size_t)blockIdx.y * aYStride;

    f32x4_t acc[4][4];
#pragma unroll
    for (int i = 0; i < 4; ++i)
#pragma unroll
        for (int j = 0; j < 4; ++j) { f32x4_t z = {0.f, 0.f, 0.f, 0.f}; acc[i][j] = z; }

    const int rA  = l >> 3;      // 0..7 row-in-group
    const int kgA = l & 7;       // 16B k-group
    const int Ktot = K1 + K2;

    for (int kc = 0; kc < Ktot; kc += 64) {
        const unsigned short* Ap; int lda, kloc;
        if (kc < K1) { Ap = A1; lda = lda1; kloc = kc; }
        else         { Ap = A2; lda = lda2; kloc = kc - K1; }
        uint4 va[4], vb[4];
#pragma unroll
        for (int i = 0; i < 4; ++i) {
            int r = w * 32 + i * 8 + rA;
            va[i] = *(const uint4*)(Ap + (row0 + r) * lda + kloc + kgA * 8);
            vb[i] = *(const uint4*)(BtB + (size_t)r * ldbt + kc + kgA * 8);
        }
        __syncthreads();   // previous-iter LDS reads done
#pragma unroll
        for (int i = 0; i < 4; ++i) {
            int r = w * 32 + i * 8 + rA;
            int swz = ((kgA ^ (r & 7)) << 4);          // XOR-swizzled byte-in-row
            *(uint4*)((char*)As + r * 128 + swz) = va[i];
            *(uint4*)((char*)Bs + r * 128 + swz) = vb[i];
        }
        __syncthreads();
        const int rsel = l & 15;
        const int kq   = l >> 4;
#pragma unroll
        for (int ks = 0; ks < 2; ++ks) {
            bf16x8_t af[4], bv[4];
#pragma unroll
            for (int fm = 0; fm < 4; ++fm) {
                int r = ((w >> 1) * 64) + fm * 16 + rsel;
                int byte = r * 128 + ((ks * 64 + kq * 16) ^ ((r & 7) << 4));
                af[fm] = *(const bf16x8_t*)((const char*)As + byte);
            }
#pragma unroll
            for (int fn = 0; fn < 4; ++fn) {
                int r = ((w & 1) * 64) + fn * 16 + rsel;
                int byte = r * 128 + ((ks * 64 + kq * 16) ^ ((r & 7) << 4));
                bv[fn] = *(const bf16x8_t*)((const char*)Bs + byte);
            }
#pragma unroll
            for (int fm = 0; fm < 4; ++fm)
#pragma unroll
                for (int fn = 0; fn < 4; ++fn)
                    acc[fm][fn] = __builtin_amdgcn_mfma_f32_16x16x32_bf16(af[fm], bv[fn], acc[fm][fn], 0, 0, 0);
        }
    }

    // ---- epilogue: frags -> swizzled LDS C-tile (bf16) -> coalesced 16B global stores ----
    __syncthreads();
    const int rg = l >> 4;
    const int cc = l & 15;
#pragma unroll
    for (int fm = 0; fm < 4; ++fm) {
#pragma unroll
        for (int r = 0; r < 4; ++r) {
            int row = (w >> 1) * 64 + fm * 16 + rg * 4 + r;
            bool zero = (mask != nullptr) && mask[row0 + row];
#pragma unroll
            for (int fn = 0; fn < 4; ++fn) {
                int col = (w & 1) * 64 + fn * 16 + cc;
                float v = acc[fm][fn][r] + (bias ? bias[colb + col] : 0.f);
                if (do_relu) v = fmaxf(v, 0.f);
                if (zero) v = 0.f;
                *(unsigned short*)(smem + row * 256 + ((col * 2) ^ ((row & 7) << 4))) = f2bf(v);
            }
        }
    }
    __syncthreads();
#pragma unroll
    for (int i = 0; i < 8; ++i) {
        int idx = tx + i * 256;
        int row = idx >> 4;
        int g   = idx & 15;
        uint4 vv = *(const uint4*)(smem + row * 256 + ((g * 16) ^ ((row & 7) << 4)));
        *(uint4*)(C + (row0 + row) * ldc + colb + g * 8) = vv;
    }
}

// ===================== aggregation: agg[n] = sum_e relu(P1[src_e] + P2'[n])  (bf16) =========
// bias pre-folded into P2' by the GEMM. XCD-chunked block swizzle for L2 locality.
__global__ void agg_k(const unsigned short* __restrict__ P12,
                      const int* __restrict__ offs, const int* __restrict__ esrc,
                      unsigned short* __restrict__ agg)
{
    int bid = blockIdx.x;
    int chunk = gridDim.x >> 3;
    int swz = (bid & 7) * chunk + (bid >> 3);
    int node = swz * 4 + (threadIdx.x >> 6);
    int l = threadIdx.x & 63;
    int beg = offs[node], end = offs[node + 1];
    unsigned p2w = *(const unsigned*)(P12 + (size_t)node * 256 + 128 + 2 * l);
    float p2a = bf2f((unsigned short)(p2w & 0xFFFF));
    float p2b = bf2f((unsigned short)(p2w >> 16));
    float aa = 0.f, ab = 0.f;
    int i = beg;
    for (; i + 1 < end; i += 2) {
        int s0 = esrc[i], s1 = esrc[i + 1];
        unsigned v0 = *(const unsigned*)(P12 + (size_t)s0 * 256 + 2 * l);
        unsigned v1 = *(const unsigned*)(P12 + (size_t)s1 * 256 + 2 * l);
        aa += fmaxf(bf2f((unsigned short)(v0 & 0xFFFF)) + p2a, 0.f);
        ab += fmaxf(bf2f((unsigned short)(v0 >> 16))    + p2b, 0.f);
        aa += fmaxf(bf2f((unsigned short)(v1 & 0xFFFF)) + p2a, 0.f);
        ab += fmaxf(bf2f((unsigned short)(v1 >> 16))    + p2b, 0.f);
    }
    if (i < end) {
        int s0 = esrc[i];
        unsigned v0 = *(const unsigned*)(P12 + (size_t)s0 * 256 + 2 * l);
        aa += fmaxf(bf2f((unsigned short)(v0 & 0xFFFF)) + p2a, 0.f);
        ab += fmaxf(bf2f((unsigned short)(v0 >> 16))    + p2b, 0.f);
    }
    unsigned o = (unsigned)f2bf(aa) | ((unsigned)f2bf(ab) << 16);
    *(unsigned*)(agg + (size_t)node * 128 + 2 * l) = o;
}

// ===================== fill x cols 128..191 (cond, temps, pad) bf16 =====================
__global__ void xfill_k(const float* __restrict__ coords, const int* __restrict__ types,
                        const unsigned char* __restrict__ maskb, unsigned short* __restrict__ x)
{
    int node = blockIdx.x * 4 + (threadIdx.x >> 6);
    int i    = threadIdx.x & 63;
    int c    = 128 + i;
    bool valid = !maskb[node];
    bool coup  = (types[node] > 0) && valid;
    float v;
    if (c < 131)       v = coup ? 0.f : coords[(size_t)node * 3 + (c - 128)];
    else if (c == 131) v = 300.f;
    else if (c == 132) v = 600.f;
    else               v = 0.f;
    x[(size_t)node * 192 + c] = f2bf(v);
}

// ===================== layer-3 (64->3) x2 + coupling transform + logdet partials ============
__global__ void final_k(const unsigned short* __restrict__ t2,
                        const float* __restrict__ Ws3, const float* __restrict__ bs3,
                        const float* __restrict__ Wt3, const float* __restrict__ bt3,
                        const float* __restrict__ coords, const int* __restrict__ types,
                        const unsigned char* __restrict__ maskb,
                        float* __restrict__ outc, float* __restrict__ partial)
{
    int tx = threadIdx.x;
    int node = blockIdx.x * 256 + tx;
    float rs0 = bs3[0], rs1 = bs3[1], rs2 = bs3[2];
    float sh0 = bt3[0], sh1 = bt3[1], sh2 = bt3[2];
    const unsigned short* a = t2 + (size_t)node * 256;
    const unsigned short* b = a + 128;
#pragma unroll 8
    for (int k = 0; k < 64; ++k) {
        float av = bf2f(a[k]), bv = bf2f(b[k]);
        rs0 += av * Ws3[k * 3 + 0]; rs1 += av * Ws3[k * 3 + 1]; rs2 += av * Ws3[k * 3 + 2];
        sh0 += bv * Wt3[k * 3 + 0]; sh1 += bv * Wt3[k * 3 + 1]; sh2 += bv * Wt3[k * 3 + 2];
    }
    bool valid = !maskb[node];
    bool coup  = (types[node] > 0) && valid;
    float c0 = coords[(size_t)node * 3 + 0];
    float c1 = coords[(size_t)node * 3 + 1];
    float c2 = coords[(size_t)node * 3 + 2];
    float ls0 = 0.f, ls1 = 0.f, ls2 = 0.f, o0 = c0, o1 = c1, o2 = c2;
    if (coup) {
        ls0 = tanhf(rs0) * 0.5f; ls1 = tanhf(rs1) * 0.5f; ls2 = tanhf(rs2) * 0.5f;
        o0 = expf(ls0) * c0 + sh0;
        o1 = expf(ls1) * c1 + sh1;
        o2 = expf(ls2) * c2 + sh2;
    }
    outc[(size_t)node * 3 + 0] = o0;
    outc[(size_t)node * 3 + 1] = o1;
    outc[(size_t)node * 3 + 2] = o2;
    __shared__ float red[256];
    red[tx] = ls0 + ls1 + ls2;
    __syncthreads();
    for (int s = 128; s > 0; s >>= 1) {
        if (tx < s) red[tx] += red[tx + s];
        __syncthreads();
    }
    if (tx == 0) partial[blockIdx.x] = red[0];
}

__global__ void red_k(const float* __restrict__ partial, float* __restrict__ ldet)
{
    __shared__ float s[256];
    int t = threadIdx.x;
    s[t] = partial[t];
    __syncthreads();
    if (t < 16) {
        float v = 0.f;
        for (int i = 0; i < 16; ++i) v += s[t * 16 + i];
        ldet[t] = v;
    }
}

// ============================================================================================
extern "C" void kernel_launch(void* const* d_in, const int* in_sizes, int n_in,
                              void* d_out, int out_size, void* d_ws, size_t ws_size,
                              hipStream_t stream)
{
    (void)in_sizes; (void)n_in; (void)out_size; (void)ws_size;
    const float* coords = (const float*)d_in[0];
    const int*   types  = (const int*)d_in[1];
    const int*   adj    = (const int*)d_in[2];
    const int*   ebi    = (const int*)d_in[3];
    const unsigned char* maskb = (const unsigned char*)d_in[4];
    const float* embed  = (const float*)d_in[5];
    const float* W_in   = (const float*)d_in[6];
    const float* b_in   = (const float*)d_in[7];
    const float* W_msg[2] = {(const float*)d_in[8],  (const float*)d_in[12]};
    const float* b_msg[2] = {(const float*)d_in[9],  (const float*)d_in[13]};
    const float* W_upd[2] = {(const float*)d_in[10], (const float*)d_in[14]};
    const float* b_upd[2] = {(const float*)d_in[11], (const float*)d_in[15]};
    const float* W_out = (const float*)d_in[16]; const float* b_out = (const float*)d_in[17];
    const float* Ws0 = (const float*)d_in[18]; const float* bs0 = (const float*)d_in[19];
    const float* Ws1 = (const float*)d_in[20]; const float* bs1 = (const float*)d_in[21];
    const float* Ws2 = (const float*)d_in[22]; const float* bs2 = (const float*)d_in[23];
    const float* Ws3 = (const float*)d_in[24]; const float* bs3 = (const float*)d_in[25];
    const float* Wt0 = (const float*)d_in[26]; const float* bt0 = (const float*)d_in[27];
    const float* Wt1 = (const float*)d_in[28]; const float* bt1 = (const float*)d_in[29];
    const float* Wt2 = (const float*)d_in[30]; const float* bt2 = (const float*)d_in[31];
    const float* Wt3 = (const float*)d_in[32]; const float* bt3 = (const float*)d_in[33];

    char* ws = (char*)d_ws;
    size_t off = 0;
    auto alloc = [&](size_t bytes) { void* p = ws + off; off += (bytes + 255) & ~(size_t)255; return p; };
    unsigned short* hf   = (unsigned short*)alloc((size_t)NNODE * 128 * 2);
    unsigned short* P12  = (unsigned short*)alloc((size_t)NNODE * 256 * 2);  // P1|P2, h1s|h1t, t2s|t2t
    unsigned short* agg  = (unsigned short*)alloc((size_t)NNODE * 128 * 2);
    unsigned short* x    = (unsigned short*)alloc((size_t)NNODE * 192 * 2);
    unsigned short* mlp  = (unsigned short*)alloc((size_t)NNODE * 256 * 2);  // h2s|h2t
    int*   deg  = (int*)alloc((size_t)NNODE * 4);
    int*   offs = (int*)alloc((size_t)(NNODE + 1) * 4);
    int*   cur  = (int*)alloc((size_t)NNODE * 4);
    int*   esrc = (int*)alloc((size_t)NE * 4);
    unsigned short* Btm0 = (unsigned short*)alloc(256 * 128 * 2);
    unsigned short* Btm1 = (unsigned short*)alloc(256 * 128 * 2);
    unsigned short* Btu0 = (unsigned short*)alloc(128 * 256 * 2);
    unsigned short* Btu1 = (unsigned short*)alloc(128 * 256 * 2);
    unsigned short* Btout  = (unsigned short*)alloc(128 * 128 * 2);
    unsigned short* Bt0cat = (unsigned short*)alloc(256 * 192 * 2);
    unsigned short* Bt1cat = (unsigned short*)alloc(256 * 128 * 2);
    unsigned short* Bt2cat = (unsigned short*)alloc(256 * 128 * 2);
    float* b0cat  = (float*)alloc(256 * 4);
    float* b1cat  = (float*)alloc(256 * 4);
    float* b2cat  = (float*)alloc(256 * 4);
    float* bm0cat = (float*)alloc(256 * 4);
    float* bm1cat = (float*)alloc(256 * 4);
    float* partial = (float*)alloc(256 * 4);

    hipMemsetAsync(deg, 0, (size_t)NNODE * 4, stream);
    hipMemsetAsync(cur, 0, (size_t)NNODE * 4, stream);

    init_k<<<NNODE / 2, 256, 0, stream>>>(types, coords, maskb, embed, W_in, b_in, hf);
    deg_k<<<NE / 256, 256, 0, stream>>>(adj, ebi, deg);
    scan_k<<<1, 1024, 0, stream>>>(deg, offs);
    scat_k<<<NE / 256, 256, 0, stream>>>(adj, ebi, offs, cur, esrc);
    prep_k<<<1029, 256, 0, stream>>>(W_msg[0], W_msg[1], W_upd[0], W_upd[1], W_out,
                                     Ws0, Wt0, Ws1, Wt1, Ws2, Wt2,
                                     bs0, bt0, bs1, bt1, bs2, bt2, b_msg[0], b_msg[1],
                                     Btm0, Btm1, Btu0, Btu1, Btout,
                                     Bt0cat, Bt1cat, Bt2cat,
                                     b0cat, b1cat, b2cat, bm0cat, bm1cat);

    const unsigned short* Btm[2] = {Btm0, Btm1};
    const unsigned short* Btu[2] = {Btu0, Btu1};
    const float* bmcat[2] = {bm0cat, bm1cat};
    for (int r = 0; r < 2; ++r) {
        mgemm_k<<<dim3(512, 2), 256, 0, stream>>>(hf, 128, 128, nullptr, 0, 0, 0,
                                                  Btm[r], 128, bmcat[r], 0, nullptr, P12, 256);
        agg_k<<<NNODE / 4, 256, 0, stream>>>(P12, offs, esrc, agg);
        mgemm_k<<<dim3(512, 1), 256, 0, stream>>>(hf, 128, 128, agg, 128, 128, 0,
                                                  Btu[r], 256, b_upd[r], 1, nullptr, hf, 128);
    }

    // node_feats -> x cols 0..127 (masked rows zeroed), then cond/temps/pad
    mgemm_k<<<dim3(512, 1), 256, 0, stream>>>(hf, 128, 128, nullptr, 0, 0, 0,
                                              Btout, 128, b_out, 0, maskb, x, 192);
    xfill_k<<<NNODE / 4, 256, 0, stream>>>(coords, types, maskb, x);

    // MLP L0: x -> [h1s|h1t] (P12);  L1: -> [h2s'|h2t'] (mlp);  L2: -> [t2s|t2t] (P12)
    mgemm_k<<<dim3(512, 2), 256, 0, stream>>>(x, 192, 192, nullptr, 0, 0, 0,
                                              Bt0cat, 192, b0cat, 1, nullptr, P12, 256);
    mgemm_k<<<dim3(512, 2), 256, 0, stream>>>(P12, 256, 128, nullptr, 0, 0, 128,
                                              Bt1cat, 128, b1cat, 1, nullptr, mlp, 256);
    mgemm_k<<<dim3(512, 2), 256, 0, stream>>>(mlp, 256, 128, nullptr, 0, 0, 128,
                                              Bt2cat, 128, b2cat, 1, nullptr, P12, 256);

    float* outc = (float*)d_out;
    final_k<<<NNODE / 256, 256, 0, stream>>>(P12, Ws3, bs3, Wt3, bt3,
                                             coords, types, maskb, outc, partial);
    red_k<<<1, 256, 0, stream>>>(partial, outc + (size_t)NNODE * 3);
}

// Round 4
// 377.405 us; speedup vs baseline: 2.1425x; 1.2956x over previous
//
#include <hip/hip_runtime.h>

#define NB    16
#define NN    4096
#define NNODE (NB*NN)   // 65536
#define NE    524288

typedef __attribute__((ext_vector_type(8))) short bf16x8_t;
typedef __attribute__((ext_vector_type(4))) float f32x4_t;

__device__ __forceinline__ unsigned short f2bf(float f) {
    union { float f; unsigned u; } v; v.f = f;
    return (unsigned short)((v.u + 0x7FFFu + ((v.u >> 16) & 1u)) >> 16);  // RNE
}
__device__ __forceinline__ float bf2f(unsigned short h) {
    union { unsigned u; float f; } v; v.u = ((unsigned)h) << 16;
    return v.f;
}

// ===================== init: h0 = relu([embed|coords] @ W_in + b_in) * vf  -> bf16 ==========
__global__ void init_k(const int* __restrict__ types, const float* __restrict__ coords,
                       const unsigned char* __restrict__ maskb,
                       const float* __restrict__ embed, const float* __restrict__ W_in,
                       const float* __restrict__ b_in, unsigned short* __restrict__ hf)
{
    int half = threadIdx.x >> 7;
    int c    = threadIdx.x & 127;
    int node = blockIdx.x * 2 + half;
    __shared__ float xs[2][8];
    if (c < 4)      xs[half][c] = embed[(size_t)types[node] * 4 + c];
    else if (c < 7) xs[half][c] = coords[(size_t)node * 3 + (c - 4)];
    __syncthreads();
    float acc = b_in[c];
#pragma unroll
    for (int k = 0; k < 7; ++k) acc += xs[half][k] * W_in[k * 128 + c];
    hf[(size_t)node * 128 + c] = maskb[node] ? (unsigned short)0 : f2bf(fmaxf(acc, 0.f));
}

// ===================== CSR build (by dst) =====================
__global__ void deg_k(const int* __restrict__ adj, const int* __restrict__ ebi, int* __restrict__ deg)
{
    int e = blockIdx.x * 256 + threadIdx.x;
    atomicAdd(&deg[ebi[e] * NN + adj[2 * e + 1]], 1);
}

__global__ void scan_k(const int* __restrict__ deg, int* __restrict__ offs)
{
    __shared__ int sums[1024];
    int t = threadIdx.x;
    int base = t * 64;
    int s = 0;
    for (int i = 0; i < 64; ++i) s += deg[base + i];
    sums[t] = s;
    __syncthreads();
    for (int off = 1; off < 1024; off <<= 1) {
        int add = (t >= off) ? sums[t - off] : 0;
        __syncthreads();
        sums[t] += add;
        __syncthreads();
    }
    int run = (t > 0) ? sums[t - 1] : 0;
    for (int i = 0; i < 64; ++i) { offs[base + i] = run; run += deg[base + i]; }
    if (t == 1023) offs[NNODE] = run;
}

__global__ void scat_k(const int* __restrict__ adj, const int* __restrict__ ebi,
                       const int* __restrict__ offs, int* __restrict__ cur, int* __restrict__ esrc)
{
    int e = blockIdx.x * 256 + threadIdx.x;
    int bb = ebi[e];
    int d = bb * NN + adj[2 * e + 1];
    int s = bb * NN + adj[2 * e + 0];
    esrc[offs[d] + atomicAdd(&cur[d], 1)] = s;
}

// ===================== weight prep: Bt[n][k] = W[k][n]  (bf16, padded/concatenated) =========
__global__ void prep_k(const float* __restrict__ Wm0, const float* __restrict__ Wm1,
                       const float* __restrict__ Wu0, const float* __restrict__ Wu1,
                       const float* __restrict__ Wout, const float* __restrict__ bOut,
                       const float* __restrict__ Ws0, const float* __restrict__ Wt0,
                       const float* __restrict__ Ws1, const float* __restrict__ Wt1,
                       const float* __restrict__ Ws2, const float* __restrict__ Wt2,
                       const float* __restrict__ bs0, const float* __restrict__ bt0,
                       const float* __restrict__ bs1, const float* __restrict__ bt1,
                       const float* __restrict__ bs2, const float* __restrict__ bt2,
                       const float* __restrict__ bm0, const float* __restrict__ bm1,
                       unsigned short* __restrict__ Btm0, unsigned short* __restrict__ Btm1,
                       unsigned short* __restrict__ Btu0, unsigned short* __restrict__ Btu1,
                       unsigned short* __restrict__ WoutP,
                       unsigned short* __restrict__ Bt0cat, unsigned short* __restrict__ Bt1cat,
                       unsigned short* __restrict__ Bt2cat,
                       float* __restrict__ b0cat, float* __restrict__ b1cat,
                       float* __restrict__ b2cat,
                       float* __restrict__ bm0cat, float* __restrict__ bm1cat,
                       float* __restrict__ bOutcat)
{
    int bid = blockIdx.x, tx = threadIdx.x;
    if (bid < 256) {            // msg: Bt [256][128]; n<128 -> Wm[k][n], n>=128 -> Wm[128+k][n-128]
        const float* W = bid < 128 ? Wm0 : Wm1;
        unsigned short* Bt = bid < 128 ? Btm0 : Btm1;
        int idx = (bid & 127) * 256 + tx;
        int n = idx >> 7, k = idx & 127;
        float v = (n < 128) ? W[k * 128 + n] : W[(128 + k) * 128 + (n - 128)];
        Bt[n * 128 + k] = f2bf(v);
    } else if (bid < 512) {     // upd: Bt [128][256] = transpose of (256x128)
        const float* W = bid < 384 ? Wu0 : Wu1;
        unsigned short* Bt = bid < 384 ? Btu0 : Btu1;
        int idx = ((bid - 256) & 127) * 256 + tx;
        int n = idx >> 8, k = idx & 255;
        Bt[n * 256 + k] = f2bf(W[k * 128 + n]);
    } else if (bid < 640) {     // WoutP [256][128], n<128 real
        int idx = (bid - 512) * 256 + tx;
        int n = idx >> 7, k = idx & 127;
        WoutP[n * 128 + k] = (n < 128) ? f2bf(Wout[k * 128 + n]) : (unsigned short)0;
    } else if (bid < 832) {     // L0 cat: [256][192], k<133 real; n<128 scale, else shift
        int idx = (bid - 640) * 256 + tx;
        int n = idx / 192, kk = idx % 192;
        const float* W = n < 128 ? Ws0 : Wt0;
        int nn = n & 127;
        Bt0cat[n * 192 + kk] = f2bf(kk < 133 ? W[kk * 128 + nn] : 0.f);
    } else if (bid < 960) {     // L1 cat: [256][128] (per-branch K)
        int idx = (bid - 832) * 256 + tx;
        int n = idx >> 7, k = idx & 127;
        const float* W = n < 128 ? Ws1 : Wt1;
        Bt1cat[n * 128 + k] = f2bf(W[k * 128 + (n & 127)]);
    } else if (bid < 1088) {    // L2 cat: [256][128], real n in [0,64) and [128,192)
        int idx = (bid - 960) * 256 + tx;
        int n = idx >> 7, k = idx & 127;
        const float* W = n < 128 ? Ws2 : Wt2;
        int nn = n & 127;
        Bt2cat[n * 128 + k] = f2bf(nn < 64 ? W[k * 64 + nn] : 0.f);
    } else if (bid == 1088) {
        b0cat[tx] = (tx < 128) ? bs0[tx] : bt0[tx - 128];
    } else if (bid == 1089) {
        b1cat[tx] = (tx < 128) ? bs1[tx] : bt1[tx - 128];
    } else if (bid == 1090) {
        int nn = tx & 127;
        b2cat[tx] = (nn < 64) ? ((tx < 128) ? bs2[nn] : bt2[nn]) : 0.f;
    } else if (bid == 1091) {
        bm0cat[tx] = (tx < 128) ? 0.f : bm0[tx - 128];
    } else if (bid == 1092) {
        bm1cat[tx] = (tx < 128) ? 0.f : bm1[tx - 128];
    } else {
        bOutcat[tx] = (tx < 128) ? bOut[tx] : 0.f;
    }
}

// ===================== bf16 MFMA GEMM (front: msg / upd), LDS-staged epilogue ===============
__launch_bounds__(256, 2)
__global__ void mgemm_k(const unsigned short* A1, int lda1, int K1,
                        const unsigned short* A2, int lda2, int K2,
                        int aYStride,
                        const unsigned short* __restrict__ Bt, int ldbt,
                        const float* __restrict__ bias, int do_relu,
                        const unsigned char* __restrict__ mask,
                        unsigned short* C, int ldc)
{
    __shared__ __align__(16) char smem[32768];
    unsigned short* As = (unsigned short*)smem;
    unsigned short* Bs = (unsigned short*)(smem + 16384);
    const int tx = threadIdx.x;
    const int w  = tx >> 6;
    const int l  = tx & 63;
    const size_t row0 = (size_t)blockIdx.x * 128;
    const int colb = blockIdx.y * 128;
    const unsigned short* BtB = Bt + (size_t)colb * ldbt;
    A1 += (size_t)blockIdx.y * aYStride;
    if (A2) A2 += (size_t)blockIdx.y * aYStride;

    f32x4_t acc[4][4];
#pragma unroll
    for (int i = 0; i < 4; ++i)
#pragma unroll
        for (int j = 0; j < 4; ++j) { f32x4_t z = {0.f, 0.f, 0.f, 0.f}; acc[i][j] = z; }

    const int rA  = l >> 3;
    const int kgA = l & 7;
    const int Ktot = K1 + K2;

    for (int kc = 0; kc < Ktot; kc += 64) {
        const unsigned short* Ap; int lda, kloc;
        if (kc < K1) { Ap = A1; lda = lda1; kloc = kc; }
        else         { Ap = A2; lda = lda2; kloc = kc - K1; }
        uint4 va[4], vb[4];
#pragma unroll
        for (int i = 0; i < 4; ++i) {
            int r = w * 32 + i * 8 + rA;
            va[i] = *(const uint4*)(Ap + (row0 + r) * lda + kloc + kgA * 8);
            vb[i] = *(const uint4*)(BtB + (size_t)r * ldbt + kc + kgA * 8);
        }
        __syncthreads();
#pragma unroll
        for (int i = 0; i < 4; ++i) {
            int r = w * 32 + i * 8 + rA;
            int swz = ((kgA ^ (r & 7)) << 4);
            *(uint4*)((char*)As + r * 128 + swz) = va[i];
            *(uint4*)((char*)Bs + r * 128 + swz) = vb[i];
        }
        __syncthreads();
        const int rsel = l & 15;
        const int kq   = l >> 4;
#pragma unroll
        for (int ks = 0; ks < 2; ++ks) {
            bf16x8_t af[4], bv[4];
#pragma unroll
            for (int fm = 0; fm < 4; ++fm) {
                int r = ((w >> 1) * 64) + fm * 16 + rsel;
                int byte = r * 128 + ((ks * 64 + kq * 16) ^ ((r & 7) << 4));
                af[fm] = *(const bf16x8_t*)((const char*)As + byte);
            }
#pragma unroll
            for (int fn = 0; fn < 4; ++fn) {
                int r = ((w & 1) * 64) + fn * 16 + rsel;
                int byte = r * 128 + ((ks * 64 + kq * 16) ^ ((r & 7) << 4));
                bv[fn] = *(const bf16x8_t*)((const char*)Bs + byte);
            }
#pragma unroll
            for (int fm = 0; fm < 4; ++fm)
#pragma unroll
                for (int fn = 0; fn < 4; ++fn)
                    acc[fm][fn] = __builtin_amdgcn_mfma_f32_16x16x32_bf16(af[fm], bv[fn], acc[fm][fn], 0, 0, 0);
        }
    }

    __syncthreads();
    const int rg = l >> 4;
    const int cc = l & 15;
#pragma unroll
    for (int fm = 0; fm < 4; ++fm) {
#pragma unroll
        for (int r = 0; r < 4; ++r) {
            int row = (w >> 1) * 64 + fm * 16 + rg * 4 + r;
            bool zero = (mask != nullptr) && mask[row0 + row];
#pragma unroll
            for (int fn = 0; fn < 4; ++fn) {
                int col = (w & 1) * 64 + fn * 16 + cc;
                float v = acc[fm][fn][r] + (bias ? bias[colb + col] : 0.f);
                if (do_relu) v = fmaxf(v, 0.f);
                if (zero) v = 0.f;
                *(unsigned short*)(smem + row * 256 + ((col * 2) ^ ((row & 7) << 4))) = f2bf(v);
            }
        }
    }
    __syncthreads();
#pragma unroll
    for (int i = 0; i < 8; ++i) {
        int idx = tx + i * 256;
        int row = idx >> 4;
        int g   = idx & 15;
        uint4 vv = *(const uint4*)(smem + row * 256 + ((g * 16) ^ ((row & 7) << 4)));
        *(uint4*)(C + (row0 + row) * ldc + colb + g * 8) = vv;
    }
}

// ===================== aggregation (bias pre-folded into P2'), XCD-chunked swizzle ==========
__global__ void agg_k(const unsigned short* __restrict__ P12,
                      const int* __restrict__ offs, const int* __restrict__ esrc,
                      unsigned short* __restrict__ agg)
{
    int bid = blockIdx.x;
    int chunk = gridDim.x >> 3;
    int swz = (bid & 7) * chunk + (bid >> 3);
    int node = swz * 4 + (threadIdx.x >> 6);
    int l = threadIdx.x & 63;
    int beg = offs[node], end = offs[node + 1];
    unsigned p2w = *(const unsigned*)(P12 + (size_t)node * 256 + 128 + 2 * l);
    float p2a = bf2f((unsigned short)(p2w & 0xFFFF));
    float p2b = bf2f((unsigned short)(p2w >> 16));
    float aa = 0.f, ab = 0.f;
    int i = beg;
    for (; i + 1 < end; i += 2) {
        int s0 = esrc[i], s1 = esrc[i + 1];
        unsigned v0 = *(const unsigned*)(P12 + (size_t)s0 * 256 + 2 * l);
        unsigned v1 = *(const unsigned*)(P12 + (size_t)s1 * 256 + 2 * l);
        aa += fmaxf(bf2f((unsigned short)(v0 & 0xFFFF)) + p2a, 0.f);
        ab += fmaxf(bf2f((unsigned short)(v0 >> 16))    + p2b, 0.f);
        aa += fmaxf(bf2f((unsigned short)(v1 & 0xFFFF)) + p2a, 0.f);
        ab += fmaxf(bf2f((unsigned short)(v1 >> 16))    + p2b, 0.f);
    }
    if (i < end) {
        int s0 = esrc[i];
        unsigned v0 = *(const unsigned*)(P12 + (size_t)s0 * 256 + 2 * l);
        aa += fmaxf(bf2f((unsigned short)(v0 & 0xFFFF)) + p2a, 0.f);
        ab += fmaxf(bf2f((unsigned short)(v0 >> 16))    + p2b, 0.f);
    }
    unsigned o = (unsigned)f2bf(aa) | ((unsigned)f2bf(ab) << 16);
    *(unsigned*)(agg + (size_t)node * 128 + 2 * l) = o;
}

// ===================== fused tail: out-GEMM + xfill + MLP L0/L1/L2/L3 + coupling ============
// 512 blocks x 512 threads (8 waves, 2x4). Per block: 128 rows, activations live in LDS.
__launch_bounds__(512, 1)
__global__ void tail_k(const unsigned short* __restrict__ hf,
                       const unsigned short* __restrict__ WoutP, const float* __restrict__ bOutcat,
                       const unsigned short* __restrict__ Bt0, const float* __restrict__ b0,
                       const unsigned short* __restrict__ Bt1, const float* __restrict__ b1,
                       const unsigned short* __restrict__ Bt2, const float* __restrict__ b2,
                       const float* __restrict__ Ws3, const float* __restrict__ bs3,
                       const float* __restrict__ Wt3, const float* __restrict__ bt3,
                       const float* __restrict__ coords, const int* __restrict__ types,
                       const unsigned char* __restrict__ maskb,
                       float* __restrict__ outc, float* __restrict__ partial)
{
    __shared__ __align__(16) char act[65536];   // 128 rows x 256 cols bf16, 512B/row, swizzled
    __shared__ __align__(16) char AsB[16384];   // out-layer A-stage; later W3 + reduce scratch
    __shared__ __align__(16) char Bs[32768];    // B chunk [256 n][64 k] bf16, 128B/row, swizzled
    const int tx = threadIdx.x;
    const int wid = tx >> 6, l = tx & 63;
    const int wr = wid >> 2, wc = wid & 3;        // wave tile: rows wr*64.., cols wc*64..
    const size_t row0 = (size_t)blockIdx.x * 128;
    const int rsel = l & 15, kq = l >> 4;
    const int rg = l >> 4, cc = l & 15;

    f32x4_t acc[4][4];

    auto zeroAcc = [&]() {
#pragma unroll
        for (int i = 0; i < 4; ++i)
#pragma unroll
            for (int j = 0; j < 4; ++j) { f32x4_t z = {0.f, 0.f, 0.f, 0.f}; acc[i][j] = z; }
    };

    auto stageB = [&](const unsigned short* __restrict__ Bt, int ldbt, int kc) {
#pragma unroll
        for (int p = 0; p < 4; ++p) {
            int idx = tx + p * 512;                 // 0..2047
            int n = idx >> 3, kg = idx & 7;
            uint4 v = *(const uint4*)(Bt + (size_t)n * ldbt + kc + kg * 8);
            *(uint4*)(Bs + n * 128 + ((kg * 16) ^ ((n & 7) << 4))) = v;
        }
    };

    auto computeChunk = [&](const char* Abase, int rowStride, int kbyte) {
#pragma unroll
        for (int ks = 0; ks < 2; ++ks) {
            bf16x8_t af[4], bv[4];
#pragma unroll
            for (int fm = 0; fm < 4; ++fm) {
                int r = wr * 64 + fm * 16 + rsel;
                int byte = r * rowStride + kbyte + ((ks * 64 + kq * 16) ^ ((r & 7) << 4));
                af[fm] = *(const bf16x8_t*)(Abase + byte);
            }
#pragma unroll
            for (int fn = 0; fn < 4; ++fn) {
                int n = wc * 64 + fn * 16 + rsel;
                int byte = n * 128 + ((ks * 64 + kq * 16) ^ ((n & 7) << 4));
                bv[fn] = *(const bf16x8_t*)(Bs + byte);
            }
#pragma unroll
            for (int fm = 0; fm < 4; ++fm)
#pragma unroll
                for (int fn = 0; fn < 4; ++fn)
                    acc[fm][fn] = __builtin_amdgcn_mfma_f32_16x16x32_bf16(af[fm], bv[fn], acc[fm][fn], 0, 0, 0);
        }
    };

    auto writeC = [&](const float* __restrict__ bias, bool relu, bool useMask) {
#pragma unroll
        for (int fm = 0; fm < 4; ++fm) {
#pragma unroll
            for (int rr = 0; rr < 4; ++rr) {
                int row = wr * 64 + fm * 16 + rg * 4 + rr;
                bool zero = useMask && maskb[row0 + row];
#pragma unroll
                for (int fn = 0; fn < 4; ++fn) {
                    int col = wc * 64 + fn * 16 + cc;
                    float v = acc[fm][fn][rr] + bias[col];
                    if (relu) v = fmaxf(v, 0.f);
                    if (zero) v = 0.f;
                    int cb = col * 2;
                    *(unsigned short*)(act + row * 512 + (cb & ~127) + ((cb & 127) ^ ((row & 7) << 4))) = f2bf(v);
                }
            }
        }
    };

    // ---- layer "out": x = hf @ WoutP + bOutcat (no relu, mask-zero rows) ----
    zeroAcc();
    for (int kc = 0; kc < 128; kc += 64) {
#pragma unroll
        for (int p = 0; p < 2; ++p) {               // stage hf chunk 128x64
            int idx = tx + p * 512;                 // 0..1023
            int r = idx >> 3, kg = idx & 7;
            uint4 v = *(const uint4*)(hf + (row0 + r) * 128 + kc + kg * 8);
            *(uint4*)(AsB + r * 128 + ((kg * 16) ^ ((r & 7) << 4))) = v;
        }
        stageB(WoutP, 128, kc);
        __syncthreads();
        computeChunk(AsB, 128, 0);
        __syncthreads();
    }
    writeC(bOutcat, false, true);
    __syncthreads();

    // ---- xfill: cols 128..191 = cond coords | temps | 0 ----
#pragma unroll
    for (int p = 0; p < 16; ++p) {
        int idx = tx + p * 512;                     // 0..8191
        int row = idx >> 6, ci = idx & 63;
        int col = 128 + ci;
        size_t node = row0 + row;
        bool coup = (types[node] > 0) && !maskb[node];
        float v;
        if (ci < 3)       v = coup ? 0.f : coords[node * 3 + ci];
        else if (ci == 3) v = 300.f;
        else if (ci == 4) v = 600.f;
        else              v = 0.f;
        int cb = col * 2;
        *(unsigned short*)(act + row * 512 + (cb & ~127) + ((cb & 127) ^ ((row & 7) << 4))) = f2bf(v);
    }
    __syncthreads();

    // ---- L0: K=192 full ----
    zeroAcc();
    for (int kc = 0; kc < 192; kc += 64) {
        stageB(Bt0, 192, kc);
        __syncthreads();
        computeChunk(act, 512, kc * 2);
        __syncthreads();
    }
    writeC(b0, true, false);
    __syncthreads();

    // ---- L1: per-branch K=128 (s: act cols 0..127, t: 128..255) ----
    const int khalf = (wc >= 2) ? 256 : 0;          // byte offset: 128 cols * 2B
    zeroAcc();
    for (int kc = 0; kc < 128; kc += 64) {
        stageB(Bt1, 128, kc);
        __syncthreads();
        computeChunk(act, 512, khalf + kc * 2);
        __syncthreads();
    }
    writeC(b1, true, false);
    __syncthreads();

    // ---- L2: per-branch K=128 ----
    zeroAcc();
    for (int kc = 0; kc < 128; kc += 64) {
        stageB(Bt2, 128, kc);
        __syncthreads();
        computeChunk(act, 512, khalf + kc * 2);
        __syncthreads();
    }
    writeC(b2, true, false);
    __syncthreads();

    // ---- L3 (64->3 x2) + coupling transform + logdet partial ----
    float* W3f = (float*)AsB;                       // [384]: Ws3 | Wt3
    if (tx < 384) W3f[tx] = (tx < 192) ? Ws3[tx] : Wt3[tx - 192];
    __syncthreads();

    int row = tx >> 2, sub = tx & 3;
    float rs0 = 0.f, rs1 = 0.f, rs2 = 0.f, sh0 = 0.f, sh1 = 0.f, sh2 = 0.f;
#pragma unroll
    for (int kk = 0; kk < 16; ++kk) {
        int k = sub * 16 + kk;
        float av = bf2f(*(const unsigned short*)(act + row * 512 + ((k * 2) ^ ((row & 7) << 4))));
        float bv = bf2f(*(const unsigned short*)(act + row * 512 + 256 + ((k * 2) ^ ((row & 7) << 4))));
        rs0 += av * W3f[k * 3 + 0]; rs1 += av * W3f[k * 3 + 1]; rs2 += av * W3f[k * 3 + 2];
        sh0 += bv * W3f[192 + k * 3 + 0]; sh1 += bv * W3f[192 + k * 3 + 1]; sh2 += bv * W3f[192 + k * 3 + 2];
    }
    rs0 += __shfl_xor(rs0, 1); rs0 += __shfl_xor(rs0, 2);
    rs1 += __shfl_xor(rs1, 1); rs1 += __shfl_xor(rs1, 2);
    rs2 += __shfl_xor(rs2, 1); rs2 += __shfl_xor(rs2, 2);
    sh0 += __shfl_xor(sh0, 1); sh0 += __shfl_xor(sh0, 2);
    sh1 += __shfl_xor(sh1, 1); sh1 += __shfl_xor(sh1, 2);
    sh2 += __shfl_xor(sh2, 1); sh2 += __shfl_xor(sh2, 2);

    float* red = (float*)(AsB + 2048);              // [128]
    if (sub == 0) {
        size_t node = row0 + row;
        bool coup = (types[node] > 0) && !maskb[node];
        float c0 = coords[node * 3 + 0], c1 = coords[node * 3 + 1], c2 = coords[node * 3 + 2];
        float ls0 = 0.f, ls1 = 0.f, ls2 = 0.f, o0 = c0, o1 = c1, o2 = c2;
        if (coup) {
            ls0 = tanhf(rs0 + bs3[0]) * 0.5f;
            ls1 = tanhf(rs1 + bs3[1]) * 0.5f;
            ls2 = tanhf(rs2 + bs3[2]) * 0.5f;
            o0 = expf(ls0) * c0 + sh0 + bt3[0];
            o1 = expf(ls1) * c1 + sh1 + bt3[1];
            o2 = expf(ls2) * c2 + sh2 + bt3[2];
        }
        outc[node * 3 + 0] = o0;
        outc[node * 3 + 1] = o1;
        outc[node * 3 + 2] = o2;
        red[row] = ls0 + ls1 + ls2;
    }
    __syncthreads();
    for (int s = 64; s > 0; s >>= 1) {
        if (tx < s) red[tx] += red[tx + s];
        __syncthreads();
    }
    if (tx == 0) partial[blockIdx.x] = red[0];
}

__global__ void red_k(const float* __restrict__ partial, float* __restrict__ ldet)
{
    __shared__ float s[512];
    int t = threadIdx.x;                            // 256
    s[t] = partial[t];
    s[t + 256] = partial[t + 256];
    __syncthreads();
    if (t < 16) {
        float v = 0.f;
        for (int i = 0; i < 32; ++i) v += s[t * 32 + i];
        ldet[t] = v;                                // block bx -> batch bx>>5 (4096/128=32)
    }
}

// ============================================================================================
extern "C" void kernel_launch(void* const* d_in, const int* in_sizes, int n_in,
                              void* d_out, int out_size, void* d_ws, size_t ws_size,
                              hipStream_t stream)
{
    (void)in_sizes; (void)n_in; (void)out_size; (void)ws_size;
    const float* coords = (const float*)d_in[0];
    const int*   types  = (const int*)d_in[1];
    const int*   adj    = (const int*)d_in[2];
    const int*   ebi    = (const int*)d_in[3];
    const unsigned char* maskb = (const unsigned char*)d_in[4];
    const float* embed  = (const float*)d_in[5];
    const float* W_in   = (const float*)d_in[6];
    const float* b_in   = (const float*)d_in[7];
    const float* W_msg[2] = {(const float*)d_in[8],  (const float*)d_in[12]};
    const float* b_msg[2] = {(const float*)d_in[9],  (const float*)d_in[13]};
    const float* W_upd[2] = {(const float*)d_in[10], (const float*)d_in[14]};
    const float* b_upd[2] = {(const float*)d_in[11], (const float*)d_in[15]};
    const float* W_out = (const float*)d_in[16]; const float* b_out = (const float*)d_in[17];
    const float* Ws0 = (const float*)d_in[18]; const float* bs0 = (const float*)d_in[19];
    const float* Ws1 = (const float*)d_in[20]; const float* bs1 = (const float*)d_in[21];
    const float* Ws2 = (const float*)d_in[22]; const float* bs2 = (const float*)d_in[23];
    const float* Ws3 = (const float*)d_in[24]; const float* bs3 = (const float*)d_in[25];
    const float* Wt0 = (const float*)d_in[26]; const float* bt0 = (const float*)d_in[27];
    const float* Wt1 = (const float*)d_in[28]; const float* bt1 = (const float*)d_in[29];
    const float* Wt2 = (const float*)d_in[30]; const float* bt2 = (const float*)d_in[31];
    const float* Wt3 = (const float*)d_in[32]; const float* bt3 = (const float*)d_in[33];

    char* ws = (char*)d_ws;
    size_t off = 0;
    auto alloc = [&](size_t bytes) { void* p = ws + off; off += (bytes + 255) & ~(size_t)255; return p; };
    unsigned short* hf   = (unsigned short*)alloc((size_t)NNODE * 128 * 2);
    unsigned short* P12  = (unsigned short*)alloc((size_t)NNODE * 256 * 2);
    unsigned short* agg  = (unsigned short*)alloc((size_t)NNODE * 128 * 2);
    int*   deg  = (int*)alloc((size_t)NNODE * 4);
    int*   offs = (int*)alloc((size_t)(NNODE + 1) * 4);
    int*   cur  = (int*)alloc((size_t)NNODE * 4);
    int*   esrc = (int*)alloc((size_t)NE * 4);
    unsigned short* Btm0 = (unsigned short*)alloc(256 * 128 * 2);
    unsigned short* Btm1 = (unsigned short*)alloc(256 * 128 * 2);
    unsigned short* Btu0 = (unsigned short*)alloc(128 * 256 * 2);
    unsigned short* Btu1 = (unsigned short*)alloc(128 * 256 * 2);
    unsigned short* WoutP  = (unsigned short*)alloc(256 * 128 * 2);
    unsigned short* Bt0cat = (unsigned short*)alloc(256 * 192 * 2);
    unsigned short* Bt1cat = (unsigned short*)alloc(256 * 128 * 2);
    unsigned short* Bt2cat = (unsigned short*)alloc(256 * 128 * 2);
    float* b0cat  = (float*)alloc(256 * 4);
    float* b1cat  = (float*)alloc(256 * 4);
    float* b2cat  = (float*)alloc(256 * 4);
    float* bm0cat = (float*)alloc(256 * 4);
    float* bm1cat = (float*)alloc(256 * 4);
    float* bOutcat = (float*)alloc(256 * 4);
    float* partial = (float*)alloc(512 * 4);

    hipMemsetAsync(deg, 0, (size_t)NNODE * 4, stream);
    hipMemsetAsync(cur, 0, (size_t)NNODE * 4, stream);

    init_k<<<NNODE / 2, 256, 0, stream>>>(types, coords, maskb, embed, W_in, b_in, hf);
    deg_k<<<NE / 256, 256, 0, stream>>>(adj, ebi, deg);
    scan_k<<<1, 1024, 0, stream>>>(deg, offs);
    scat_k<<<NE / 256, 256, 0, stream>>>(adj, ebi, offs, cur, esrc);
    prep_k<<<1094, 256, 0, stream>>>(W_msg[0], W_msg[1], W_upd[0], W_upd[1], W_out, b_out,
                                     Ws0, Wt0, Ws1, Wt1, Ws2, Wt2,
                                     bs0, bt0, bs1, bt1, bs2, bt2, b_msg[0], b_msg[1],
                                     Btm0, Btm1, Btu0, Btu1, WoutP,
                                     Bt0cat, Bt1cat, Bt2cat,
                                     b0cat, b1cat, b2cat, bm0cat, bm1cat, bOutcat);

    const unsigned short* Btm[2] = {Btm0, Btm1};
    const unsigned short* Btu[2] = {Btu0, Btu1};
    const float* bmcat[2] = {bm0cat, bm1cat};
    for (int r = 0; r < 2; ++r) {
        mgemm_k<<<dim3(512, 2), 256, 0, stream>>>(hf, 128, 128, nullptr, 0, 0, 0,
                                                  Btm[r], 128, bmcat[r], 0, nullptr, P12, 256);
        agg_k<<<NNODE / 4, 256, 0, stream>>>(P12, offs, esrc, agg);
        mgemm_k<<<dim3(512, 1), 256, 0, stream>>>(hf, 128, 128, agg, 128, 128, 0,
                                                  Btu[r], 256, b_upd[r], 1, nullptr, hf, 128);
    }

    float* outc = (float*)d_out;
    tail_k<<<512, 512, 0, stream>>>(hf, WoutP, bOutcat,
                                    Bt0cat, b0cat, Bt1cat, b1cat, Bt2cat, b2cat,
                                    Ws3, bs3, Wt3, bt3,
                                    coords, types, maskb, outc, partial);
    red_k<<<1, 256, 0, stream>>>(partial, outc + (size_t)NNODE * 3);
}

// Round 7
// 260.128 us; speedup vs baseline: 3.1084x; 1.4508x over previous
//
#include <hip/hip_runtime.h>

#define NB    16
#define NN    4096
#define NNODE (NB*NN)   // 65536
#define NE    524288

typedef __attribute__((ext_vector_type(8))) short bf16x8_t;
typedef __attribute__((ext_vector_type(4))) float f32x4_t;

__device__ __forceinline__ unsigned short f2bf(float f) {
    union { float f; unsigned u; } v; v.f = f;
    return (unsigned short)((v.u + 0x7FFFu + ((v.u >> 16) & 1u)) >> 16);  // RNE
}
__device__ __forceinline__ float bf2f(unsigned short h) {
    union { unsigned u; float f; } v; v.u = ((unsigned)h) << 16;
    return v.f;
}

// ===================== CSR build (by dst) =====================
__global__ void deg_k(const int* __restrict__ adj, const int* __restrict__ ebi, int* __restrict__ deg)
{
    int e = blockIdx.x * 256 + threadIdx.x;
    atomicAdd(&deg[ebi[e] * NN + adj[2 * e + 1]], 1);
}

__global__ void scan_k(const int* __restrict__ deg, int* __restrict__ offs)
{
    __shared__ int sums[1024];
    int t = threadIdx.x;
    int base = t * 64;
    int s = 0;
    for (int i = 0; i < 64; ++i) s += deg[base + i];
    sums[t] = s;
    __syncthreads();
    for (int off = 1; off < 1024; off <<= 1) {
        int add = (t >= off) ? sums[t - off] : 0;
        __syncthreads();
        sums[t] += add;
        __syncthreads();
    }
    int run = (t > 0) ? sums[t - 1] : 0;
    for (int i = 0; i < 64; ++i) { offs[base + i] = run; run += deg[base + i]; }
    if (t == 1023) offs[NNODE] = run;
}

__global__ void scat_k(const int* __restrict__ adj, const int* __restrict__ ebi,
                       const int* __restrict__ offs, int* __restrict__ cur, int* __restrict__ esrc)
{
    int e = blockIdx.x * 256 + threadIdx.x;
    int bb = ebi[e];
    int d = bb * NN + adj[2 * e + 1];
    int s = bb * NN + adj[2 * e + 0];
    esrc[offs[d] + atomicAdd(&cur[d], 1)] = s;
}

// ===================== weight prep =====================
__global__ void prep_k(const float* __restrict__ Wm0, const float* __restrict__ Wm1,
                       const float* __restrict__ Wu0, const float* __restrict__ Wu1,
                       const float* __restrict__ Wout,
                       const float* __restrict__ Ws0, const float* __restrict__ Wt0,
                       const float* __restrict__ Ws1, const float* __restrict__ Wt1,
                       const float* __restrict__ Ws2, const float* __restrict__ Wt2,
                       const float* __restrict__ bs0, const float* __restrict__ bt0,
                       const float* __restrict__ bs1, const float* __restrict__ bt1,
                       const float* __restrict__ bs2, const float* __restrict__ bt2,
                       const float* __restrict__ bm0, const float* __restrict__ bm1,
                       unsigned short* __restrict__ Btm0, unsigned short* __restrict__ Btm1,
                       unsigned short* __restrict__ Btu0, unsigned short* __restrict__ Btu1,
                       unsigned short* __restrict__ WoutP,
                       unsigned short* __restrict__ Bt0cat, unsigned short* __restrict__ Bt1cat,
                       unsigned short* __restrict__ Bt2cat,
                       float* __restrict__ b0cat, float* __restrict__ b1cat,
                       float* __restrict__ b2cat,
                       float* __restrict__ bm0cat, float* __restrict__ bm1cat)
{
    int bid = blockIdx.x, tx = threadIdx.x;
    if (bid < 256) {            // msg: Bt [256][128]
        const float* W = bid < 128 ? Wm0 : Wm1;
        unsigned short* Bt = bid < 128 ? Btm0 : Btm1;
        int idx = (bid & 127) * 256 + tx;
        int n = idx >> 7, k = idx & 127;
        float v = (n < 128) ? W[k * 128 + n] : W[(128 + k) * 128 + (n - 128)];
        Bt[n * 128 + k] = f2bf(v);
    } else if (bid < 512) {     // upd: Bt [128][256]
        const float* W = bid < 384 ? Wu0 : Wu1;
        unsigned short* Bt = bid < 384 ? Btu0 : Btu1;
        int idx = ((bid - 256) & 127) * 256 + tx;
        int n = idx >> 8, k = idx & 255;
        Bt[n * 256 + k] = f2bf(W[k * 128 + n]);
    } else if (bid < 576) {     // WoutP [128][128]
        int idx = (bid - 512) * 256 + tx;
        int n = idx >> 7, k = idx & 127;
        WoutP[n * 128 + k] = f2bf(Wout[k * 128 + n]);
    } else if (bid < 768) {     // L0 cat: [256][192], k<133 real
        int idx = (bid - 576) * 256 + tx;
        int n = idx / 192, kk = idx % 192;
        const float* W = n < 128 ? Ws0 : Wt0;
        int nn = n & 127;
        Bt0cat[n * 192 + kk] = f2bf(kk < 133 ? W[kk * 128 + nn] : 0.f);
    } else if (bid < 896) {     // L1 cat: [256][128]
        int idx = (bid - 768) * 256 + tx;
        int n = idx >> 7, k = idx & 127;
        const float* W = n < 128 ? Ws1 : Wt1;
        Bt1cat[n * 128 + k] = f2bf(W[k * 128 + (n & 127)]);
    } else if (bid < 1024) {    // L2 cat: [256][128], real n in [0,64) and [128,192)
        int idx = (bid - 896) * 256 + tx;
        int n = idx >> 7, k = idx & 127;
        const float* W = n < 128 ? Ws2 : Wt2;
        int nn = n & 127;
        Bt2cat[n * 128 + k] = f2bf(nn < 64 ? W[k * 64 + nn] : 0.f);
    } else if (bid == 1024) {
        b0cat[tx] = (tx < 128) ? bs0[tx] : bt0[tx - 128];
    } else if (bid == 1025) {
        b1cat[tx] = (tx < 128) ? bs1[tx] : bt1[tx - 128];
    } else if (bid == 1026) {
        int nn = tx & 127;
        b2cat[tx] = (nn < 64) ? ((tx < 128) ? bs2[nn] : bt2[nn]) : 0.f;
    } else if (bid == 1027) {
        bm0cat[tx] = (tx < 128) ? 0.f : bm0[tx - 128];
    } else {
        bm1cat[tx] = (tx < 128) ? 0.f : bm1[tx - 128];
    }
}

// ===================== msg GEMM phase: P12[rows] = act(K=128) @ Bt^T (N=256) + bias =========
// act: LDS 64x128 bf16 swizzled (stride 256B). Bs reused as C staging.
__device__ __forceinline__ void msg_phase(const char* act, char* Bs,
    const unsigned short* __restrict__ Bt, const float* __restrict__ bias,
    unsigned short* __restrict__ P12, size_t row0, int tx)
{
    const int wid = tx >> 6, l = tx & 63;
    const int wr = wid >> 1, wc = wid & 1;
    const int rsel = l & 15, kq = l >> 4;
    const int rg = l >> 4, cc = l & 15;
#pragma unroll
    for (int nh = 0; nh < 2; ++nh) {
        f32x4_t acc[2][4];
#pragma unroll
        for (int i = 0; i < 2; ++i)
#pragma unroll
            for (int j = 0; j < 4; ++j) { f32x4_t z = {0.f,0.f,0.f,0.f}; acc[i][j] = z; }
#pragma unroll
        for (int kc = 0; kc < 128; kc += 64) {
            __syncthreads();
#pragma unroll
            for (int p = 0; p < 4; ++p) {
                int idx = tx + p * 256;
                int n = idx >> 3, kg = idx & 7;
                uint4 v = *(const uint4*)(Bt + (size_t)(nh * 128 + n) * 128 + kc + kg * 8);
                *(uint4*)(Bs + n * 128 + ((kg * 16) ^ ((n & 7) << 4))) = v;
            }
            __syncthreads();
#pragma unroll
            for (int ks = 0; ks < 2; ++ks) {
                bf16x8_t af[2], bv[4];
#pragma unroll
                for (int fm = 0; fm < 2; ++fm) {
                    int r = wr * 32 + fm * 16 + rsel;
                    af[fm] = *(const bf16x8_t*)(act + r * 256 + kc * 2 + ((ks * 64 + kq * 16) ^ ((r & 7) << 4)));
                }
#pragma unroll
                for (int fn = 0; fn < 4; ++fn) {
                    int n = wc * 64 + fn * 16 + rsel;
                    bv[fn] = *(const bf16x8_t*)(Bs + n * 128 + ((ks * 64 + kq * 16) ^ ((n & 7) << 4)));
                }
#pragma unroll
                for (int fm = 0; fm < 2; ++fm)
#pragma unroll
                    for (int fn = 0; fn < 4; ++fn)
                        acc[fm][fn] = __builtin_amdgcn_mfma_f32_16x16x32_bf16(af[fm], bv[fn], acc[fm][fn], 0, 0, 0);
            }
        }
        __syncthreads();                // all Bs reads done -> reuse as C stage
#pragma unroll
        for (int fm = 0; fm < 2; ++fm)
#pragma unroll
            for (int rr = 0; rr < 4; ++rr) {
                int row = wr * 32 + fm * 16 + rg * 4 + rr;
#pragma unroll
                for (int fn = 0; fn < 4; ++fn) {
                    int col = wc * 64 + fn * 16 + cc;
                    float v = acc[fm][fn][rr] + bias[nh * 128 + col];
                    int cb = col * 2;
                    *(unsigned short*)(Bs + row * 256 + (cb & ~127) + ((cb & 127) ^ ((row & 7) << 4))) = f2bf(v);
                }
            }
        __syncthreads();
#pragma unroll
        for (int p = 0; p < 4; ++p) {
            int idx = tx + p * 256;
            int row = idx >> 4, g = idx & 15;
            int pb = g * 16;
            uint4 v = *(const uint4*)(Bs + row * 256 + (pb & ~127) + ((pb & 127) ^ ((row & 7) << 4)));
            *(uint4*)(P12 + (row0 + row) * 256 + nh * 128 + g * 8) = v;
        }
    }
}

// ===================== fused init + msg0 =====================
__launch_bounds__(256, 4)
__global__ void fused_im_k(const int* __restrict__ types, const float* __restrict__ coords,
                           const unsigned char* __restrict__ maskb,
                           const float* __restrict__ embed, const float* __restrict__ W_in,
                           const float* __restrict__ b_in,
                           const unsigned short* __restrict__ Btm, const float* __restrict__ bmcat,
                           unsigned short* __restrict__ hf, unsigned short* __restrict__ P12)
{
    __shared__ __align__(16) char act[16384];   // 64 x 128 bf16, stride 256B
    __shared__ __align__(16) char Bs[16384];
    const int tx = threadIdx.x;
    const size_t row0 = (size_t)blockIdx.x * 64;

    // phase 1: h0 = relu([embed|coords] @ W_in + b_in) * vf
    float* wf = (float*)Bs;             // [8][128]: rows 0..6 = W_in, row 7 = b_in
    float* xs = (float*)(Bs + 4096);    // [64][8]
#pragma unroll
    for (int p = 0; p < 4; ++p) {
        int idx = tx + p * 256;
        int k = idx >> 7, c = idx & 127;
        wf[idx] = (k < 7) ? W_in[k * 128 + c] : b_in[c];
    }
    if (tx < 64) {
        size_t node = row0 + tx;
        int tp = types[node];
#pragma unroll
        for (int j = 0; j < 4; ++j) xs[tx * 8 + j] = embed[(size_t)tp * 4 + j];
#pragma unroll
        for (int j = 0; j < 3; ++j) xs[tx * 8 + 4 + j] = coords[node * 3 + j];
    }
    __syncthreads();
    {
        int row = tx >> 2, c0 = (tx & 3) * 32;
        float x0 = xs[row*8+0], x1 = xs[row*8+1], x2 = xs[row*8+2], x3 = xs[row*8+3];
        float x4 = xs[row*8+4], x5 = xs[row*8+5], x6 = xs[row*8+6];
        bool msk = maskb[row0 + row];
        int swz = (row & 7) << 4;
#pragma unroll
        for (int c = 0; c < 32; ++c) {
            int col = c0 + c;
            float a = wf[7*128+col] + x0*wf[col] + x1*wf[128+col] + x2*wf[256+col]
                    + x3*wf[384+col] + x4*wf[512+col] + x5*wf[640+col] + x6*wf[768+col];
            a = msk ? 0.f : fmaxf(a, 0.f);
            int cb = col * 2;
            *(unsigned short*)(act + row * 256 + (cb & ~127) + ((cb & 127) ^ swz)) = f2bf(a);
        }
    }
    __syncthreads();
    // write h0 to global hf (coalesced)
#pragma unroll
    for (int p = 0; p < 4; ++p) {
        int idx = tx + p * 256;
        int row = idx >> 4, g = idx & 15;
        int pb = g * 16;
        uint4 v = *(const uint4*)(act + row * 256 + (pb & ~127) + ((pb & 127) ^ ((row & 7) << 4)));
        *(uint4*)(hf + (row0 + row) * 128 + g * 8) = v;
    }
    // phase 2: P12 = h0 @ Btm^T + bmcat
    msg_phase(act, Bs, Btm, bmcat, P12, row0, tx);
}

// ===================== fused upd + msg(next) =====================
__launch_bounds__(256, 4)
__global__ void fused_um_k(const unsigned short* __restrict__ hfin,
                           const unsigned short* __restrict__ aggp,
                           const unsigned short* __restrict__ Btu, const float* __restrict__ bu,
                           const unsigned short* __restrict__ Btm, const float* __restrict__ bmcat,
                           unsigned short* __restrict__ hfout, unsigned short* __restrict__ P12)
{
    __shared__ __align__(16) char act[16384];   // hf_new 64 x 128
    __shared__ __align__(16) char Bs[16384];
    const int tx = threadIdx.x;
    const int wid = tx >> 6, l = tx & 63;
    const int wr = wid >> 1, wc = wid & 1;
    const int rsel = l & 15, kq = l >> 4, rg = l >> 4, cc = l & 15;
    const size_t row0 = (size_t)blockIdx.x * 64;

    // phase 1: hf_new = relu([hf|agg] @ Btu^T + bu), A-frags direct from global
    f32x4_t acc[2][4];
#pragma unroll
    for (int i = 0; i < 2; ++i)
#pragma unroll
        for (int j = 0; j < 4; ++j) { f32x4_t z = {0.f,0.f,0.f,0.f}; acc[i][j] = z; }
#pragma unroll
    for (int kc = 0; kc < 256; kc += 64) {
        const unsigned short* Ap = (kc < 128) ? hfin : aggp;
        int kloc = (kc < 128) ? kc : kc - 128;
        __syncthreads();
#pragma unroll
        for (int p = 0; p < 4; ++p) {
            int idx = tx + p * 256;
            int n = idx >> 3, kg = idx & 7;
            uint4 v = *(const uint4*)(Btu + (size_t)n * 256 + kc + kg * 8);
            *(uint4*)(Bs + n * 128 + ((kg * 16) ^ ((n & 7) << 4))) = v;
        }
        __syncthreads();
#pragma unroll
        for (int ks = 0; ks < 2; ++ks) {
            bf16x8_t af[2], bv[4];
#pragma unroll
            for (int fm = 0; fm < 2; ++fm) {
                size_t r = row0 + wr * 32 + fm * 16 + rsel;
                af[fm] = *(const bf16x8_t*)(Ap + r * 128 + kloc + ks * 32 + kq * 8);
            }
#pragma unroll
            for (int fn = 0; fn < 4; ++fn) {
                int n = wc * 64 + fn * 16 + rsel;
                bv[fn] = *(const bf16x8_t*)(Bs + n * 128 + ((ks * 64 + kq * 16) ^ ((n & 7) << 4)));
            }
#pragma unroll
            for (int fm = 0; fm < 2; ++fm)
#pragma unroll
                for (int fn = 0; fn < 4; ++fn)
                    acc[fm][fn] = __builtin_amdgcn_mfma_f32_16x16x32_bf16(af[fm], bv[fn], acc[fm][fn], 0, 0, 0);
        }
    }
#pragma unroll
    for (int fm = 0; fm < 2; ++fm)
#pragma unroll
        for (int rr = 0; rr < 4; ++rr) {
            int row = wr * 32 + fm * 16 + rg * 4 + rr;
#pragma unroll
            for (int fn = 0; fn < 4; ++fn) {
                int col = wc * 64 + fn * 16 + cc;
                float v = fmaxf(acc[fm][fn][rr] + bu[col], 0.f);
                int cb = col * 2;
                *(unsigned short*)(act + row * 256 + (cb & ~127) + ((cb & 127) ^ ((row & 7) << 4))) = f2bf(v);
            }
        }
    __syncthreads();
    // write hf_new to global
#pragma unroll
    for (int p = 0; p < 4; ++p) {
        int idx = tx + p * 256;
        int row = idx >> 4, g = idx & 15;
        int pb = g * 16;
        uint4 v = *(const uint4*)(act + row * 256 + (pb & ~127) + ((pb & 127) ^ ((row & 7) << 4)));
        *(uint4*)(hfout + (row0 + row) * 128 + g * 8) = v;
    }
    // phase 2: P12 = hf_new @ Btm^T + bmcat
    msg_phase(act, Bs, Btm, bmcat, P12, row0, tx);
}

// ===================== aggregation (bias pre-folded), XCD-chunked swizzle =====================
__global__ void agg_k(const unsigned short* __restrict__ P12,
                      const int* __restrict__ offs, const int* __restrict__ esrc,
                      unsigned short* __restrict__ agg)
{
    int bid = blockIdx.x;
    int chunk = gridDim.x >> 3;
    int swz = (bid & 7) * chunk + (bid >> 3);
    int node = swz * 4 + (threadIdx.x >> 6);
    int l = threadIdx.x & 63;
    int beg = offs[node], end = offs[node + 1];
    unsigned p2w = *(const unsigned*)(P12 + (size_t)node * 256 + 128 + 2 * l);
    float p2a = bf2f((unsigned short)(p2w & 0xFFFF));
    float p2b = bf2f((unsigned short)(p2w >> 16));
    float aa = 0.f, ab = 0.f;
    int i = beg;
    for (; i + 3 < end; i += 4) {
        int s0 = esrc[i], s1 = esrc[i+1], s2 = esrc[i+2], s3 = esrc[i+3];
        unsigned v0 = *(const unsigned*)(P12 + (size_t)s0 * 256 + 2 * l);
        unsigned v1 = *(const unsigned*)(P12 + (size_t)s1 * 256 + 2 * l);
        unsigned v2 = *(const unsigned*)(P12 + (size_t)s2 * 256 + 2 * l);
        unsigned v3 = *(const unsigned*)(P12 + (size_t)s3 * 256 + 2 * l);
        aa += fmaxf(bf2f((unsigned short)(v0 & 0xFFFF)) + p2a, 0.f);
        ab += fmaxf(bf2f((unsigned short)(v0 >> 16))    + p2b, 0.f);
        aa += fmaxf(bf2f((unsigned short)(v1 & 0xFFFF)) + p2a, 0.f);
        ab += fmaxf(bf2f((unsigned short)(v1 >> 16))    + p2b, 0.f);
        aa += fmaxf(bf2f((unsigned short)(v2 & 0xFFFF)) + p2a, 0.f);
        ab += fmaxf(bf2f((unsigned short)(v2 >> 16))    + p2b, 0.f);
        aa += fmaxf(bf2f((unsigned short)(v3 & 0xFFFF)) + p2a, 0.f);
        ab += fmaxf(bf2f((unsigned short)(v3 >> 16))    + p2b, 0.f);
    }
    for (; i < end; ++i) {
        int s0 = esrc[i];
        unsigned v0 = *(const unsigned*)(P12 + (size_t)s0 * 256 + 2 * l);
        aa += fmaxf(bf2f((unsigned short)(v0 & 0xFFFF)) + p2a, 0.f);
        ab += fmaxf(bf2f((unsigned short)(v0 >> 16))    + p2b, 0.f);
    }
    unsigned o = (unsigned)f2bf(aa) | ((unsigned)f2bf(ab) << 16);
    *(unsigned*)(agg + (size_t)node * 128 + 2 * l) = o;
}

// ===================== fused upd1 + out + xfill + MLP + coupling =====================
__launch_bounds__(256, 2)
__global__ void fused_ut_k(const unsigned short* __restrict__ hfin,
                           const unsigned short* __restrict__ aggp,
                           const unsigned short* __restrict__ Btu, const float* __restrict__ bu,
                           const unsigned short* __restrict__ WoutP, const float* __restrict__ bOut,
                           const unsigned short* __restrict__ Bt0, const float* __restrict__ b0,
                           const unsigned short* __restrict__ Bt1, const float* __restrict__ b1,
                           const unsigned short* __restrict__ Bt2, const float* __restrict__ b2,
                           const float* __restrict__ Ws3, const float* __restrict__ bs3,
                           const float* __restrict__ Wt3, const float* __restrict__ bt3,
                           const float* __restrict__ coords, const int* __restrict__ types,
                           const unsigned char* __restrict__ maskb,
                           float* __restrict__ outc, float* __restrict__ partial)
{
    __shared__ __align__(16) char act[32768];   // 64 x 256 bf16, stride 512B
    __shared__ __align__(16) char hfn[16384];   // 64 x 128 bf16, stride 256B (later W3/red)
    __shared__ __align__(16) char Bs[32768];    // up to [256][64]
    const int tx = threadIdx.x;
    const int wid = tx >> 6, l = tx & 63;
    const int rsel = l & 15, kq = l >> 4, rg = l >> 4, cc = l & 15;
    const size_t row0 = (size_t)blockIdx.x * 64;

    // ---- phase 1: upd1 -> hfn (A-frags direct from global) ----
    {
        const int wr = wid >> 1, wc = wid & 1;
        f32x4_t acc[2][4];
#pragma unroll
        for (int i = 0; i < 2; ++i)
#pragma unroll
            for (int j = 0; j < 4; ++j) { f32x4_t z = {0.f,0.f,0.f,0.f}; acc[i][j] = z; }
#pragma unroll
        for (int kc = 0; kc < 256; kc += 64) {
            const unsigned short* Ap = (kc < 128) ? hfin : aggp;
            int kloc = (kc < 128) ? kc : kc - 128;
            __syncthreads();
#pragma unroll
            for (int p = 0; p < 4; ++p) {
                int idx = tx + p * 256;
                int n = idx >> 3, kg = idx & 7;
                uint4 v = *(const uint4*)(Btu + (size_t)n * 256 + kc + kg * 8);
                *(uint4*)(Bs + n * 128 + ((kg * 16) ^ ((n & 7) << 4))) = v;
            }
            __syncthreads();
#pragma unroll
            for (int ks = 0; ks < 2; ++ks) {
                bf16x8_t af[2], bv[4];
#pragma unroll
                for (int fm = 0; fm < 2; ++fm) {
                    size_t r = row0 + wr * 32 + fm * 16 + rsel;
                    af[fm] = *(const bf16x8_t*)(Ap + r * 128 + kloc + ks * 32 + kq * 8);
                }
#pragma unroll
                for (int fn = 0; fn < 4; ++fn) {
                    int n = wc * 64 + fn * 16 + rsel;
                    bv[fn] = *(const bf16x8_t*)(Bs + n * 128 + ((ks * 64 + kq * 16) ^ ((n & 7) << 4)));
                }
#pragma unroll
                for (int fm = 0; fm < 2; ++fm)
#pragma unroll
                    for (int fn = 0; fn < 4; ++fn)
                        acc[fm][fn] = __builtin_amdgcn_mfma_f32_16x16x32_bf16(af[fm], bv[fn], acc[fm][fn], 0, 0, 0);
            }
        }
#pragma unroll
        for (int fm = 0; fm < 2; ++fm)
#pragma unroll
            for (int rr = 0; rr < 4; ++rr) {
                int row = wr * 32 + fm * 16 + rg * 4 + rr;
#pragma unroll
                for (int fn = 0; fn < 4; ++fn) {
                    int col = wc * 64 + fn * 16 + cc;
                    float v = fmaxf(acc[fm][fn][rr] + bu[col], 0.f);
                    int cb = col * 2;
                    *(unsigned short*)(hfn + row * 256 + (cb & ~127) + ((cb & 127) ^ ((row & 7) << 4))) = f2bf(v);
                }
            }
    }
    __syncthreads();

    // ---- phase 2: node_feats -> act cols 0..127 (mask-zero rows) ----
    {
        const int wr = wid >> 1, wc = wid & 1;
        f32x4_t acc[2][4];
#pragma unroll
        for (int i = 0; i < 2; ++i)
#pragma unroll
            for (int j = 0; j < 4; ++j) { f32x4_t z = {0.f,0.f,0.f,0.f}; acc[i][j] = z; }
#pragma unroll
        for (int kc = 0; kc < 128; kc += 64) {
            __syncthreads();
#pragma unroll
            for (int p = 0; p < 4; ++p) {
                int idx = tx + p * 256;
                int n = idx >> 3, kg = idx & 7;
                uint4 v = *(const uint4*)(WoutP + (size_t)n * 128 + kc + kg * 8);
                *(uint4*)(Bs + n * 128 + ((kg * 16) ^ ((n & 7) << 4))) = v;
            }
            __syncthreads();
#pragma unroll
            for (int ks = 0; ks < 2; ++ks) {
                bf16x8_t af[2], bv[4];
#pragma unroll
                for (int fm = 0; fm < 2; ++fm) {
                    int r = wr * 32 + fm * 16 + rsel;
                    af[fm] = *(const bf16x8_t*)(hfn + r * 256 + kc * 2 + ((ks * 64 + kq * 16) ^ ((r & 7) << 4)));
                }
#pragma unroll
                for (int fn = 0; fn < 4; ++fn) {
                    int n = wc * 64 + fn * 16 + rsel;
                    bv[fn] = *(const bf16x8_t*)(Bs + n * 128 + ((ks * 64 + kq * 16) ^ ((n & 7) << 4)));
                }
#pragma unroll
                for (int fm = 0; fm < 2; ++fm)
#pragma unroll
                    for (int fn = 0; fn < 4; ++fn)
                        acc[fm][fn] = __builtin_amdgcn_mfma_f32_16x16x32_bf16(af[fm], bv[fn], acc[fm][fn], 0, 0, 0);
            }
        }
#pragma unroll
        for (int fm = 0; fm < 2; ++fm)
#pragma unroll
            for (int rr = 0; rr < 4; ++rr) {
                int row = wr * 32 + fm * 16 + rg * 4 + rr;
                bool zero = maskb[row0 + row];
#pragma unroll
                for (int fn = 0; fn < 4; ++fn) {
                    int col = wc * 64 + fn * 16 + cc;
                    float v = acc[fm][fn][rr] + bOut[col];
                    if (zero) v = 0.f;
                    int cb = col * 2;
                    *(unsigned short*)(act + row * 512 + (cb & ~127) + ((cb & 127) ^ ((row & 7) << 4))) = f2bf(v);
                }
            }
    }
    // ---- xfill: act cols 128..191 ----
#pragma unroll
    for (int p = 0; p < 16; ++p) {
        int idx = tx + p * 256;
        int row = idx >> 6, ci = idx & 63;
        int col = 128 + ci;
        size_t node = row0 + row;
        bool coup = (types[node] > 0) && !maskb[node];
        float v;
        if (ci < 3)       v = coup ? 0.f : coords[node * 3 + ci];
        else if (ci == 3) v = 300.f;
        else if (ci == 4) v = 600.f;
        else              v = 0.f;
        int cb = col * 2;
        *(unsigned short*)(act + row * 512 + (cb & ~127) + ((cb & 127) ^ ((row & 7) << 4))) = f2bf(v);
    }
    __syncthreads();

    // ---- L0 (K=192, N=256), L1, L2 (per-branch K=128, N=256) ----
    const int wr = wid >> 1, wc = wid & 1;   // wave tile: 32 rows x 128 cols
#pragma unroll
    for (int layer = 0; layer < 3; ++layer) {
        const unsigned short* Bt = layer == 0 ? Bt0 : (layer == 1 ? Bt1 : Bt2);
        const float* bb = layer == 0 ? b0 : (layer == 1 ? b1 : b2);
        const int ldbt = layer == 0 ? 192 : 128;
        const int Ktot = layer == 0 ? 192 : 128;
        const int kbase = (layer == 0) ? 0 : (wc ? 256 : 0);   // branch K offset (bytes)
        f32x4_t acc[2][8];
#pragma unroll
        for (int i = 0; i < 2; ++i)
#pragma unroll
            for (int j = 0; j < 8; ++j) { f32x4_t z = {0.f,0.f,0.f,0.f}; acc[i][j] = z; }
        for (int kc = 0; kc < Ktot; kc += 64) {
            __syncthreads();
#pragma unroll
            for (int p = 0; p < 8; ++p) {
                int idx = tx + p * 256;
                int n = idx >> 3, kg = idx & 7;
                uint4 v = *(const uint4*)(Bt + (size_t)n * ldbt + kc + kg * 8);
                *(uint4*)(Bs + n * 128 + ((kg * 16) ^ ((n & 7) << 4))) = v;
            }
            __syncthreads();
#pragma unroll
            for (int ks = 0; ks < 2; ++ks) {
                bf16x8_t af[2], bv[8];
#pragma unroll
                for (int fm = 0; fm < 2; ++fm) {
                    int r = wr * 32 + fm * 16 + rsel;
                    af[fm] = *(const bf16x8_t*)(act + r * 512 + kbase + kc * 2 + ((ks * 64 + kq * 16) ^ ((r & 7) << 4)));
                }
#pragma unroll
                for (int fn = 0; fn < 8; ++fn) {
                    int n = wc * 128 + fn * 16 + rsel;
                    bv[fn] = *(const bf16x8_t*)(Bs + n * 128 + ((ks * 64 + kq * 16) ^ ((n & 7) << 4)));
                }
#pragma unroll
                for (int fm = 0; fm < 2; ++fm)
#pragma unroll
                    for (int fn = 0; fn < 8; ++fn)
                        acc[fm][fn] = __builtin_amdgcn_mfma_f32_16x16x32_bf16(af[fm], bv[fn], acc[fm][fn], 0, 0, 0);
            }
        }
        __syncthreads();               // all act reads done before in-place write
#pragma unroll
        for (int fm = 0; fm < 2; ++fm)
#pragma unroll
            for (int rr = 0; rr < 4; ++rr) {
                int row = wr * 32 + fm * 16 + rg * 4 + rr;
#pragma unroll
                for (int fn = 0; fn < 8; ++fn) {
                    int col = wc * 128 + fn * 16 + cc;
                    float v = fmaxf(acc[fm][fn][rr] + bb[col], 0.f);
                    int cb = col * 2;
                    *(unsigned short*)(act + row * 512 + (cb & ~127) + ((cb & 127) ^ ((row & 7) << 4))) = f2bf(v);
                }
            }
        __syncthreads();
    }

    // ---- L3 (64->3 x2) + coupling + logdet partial ----
    float* W3f = (float*)hfn;                   // [384]
    float* red = (float*)(hfn + 2048);          // [64]
    for (int i = tx; i < 384; i += 256)         // FIX: 256 threads must cover 384 entries
        W3f[i] = (i < 192) ? Ws3[i] : Wt3[i - 192];
    __syncthreads();
    {
        int row = tx >> 2, sub = tx & 3;
        int swz = (row & 7) << 4;
        float rs0 = 0.f, rs1 = 0.f, rs2 = 0.f, sh0 = 0.f, sh1 = 0.f, sh2 = 0.f;
#pragma unroll
        for (int kk = 0; kk < 16; ++kk) {
            int k = sub * 16 + kk;
            float av = bf2f(*(const unsigned short*)(act + row * 512 + ((k * 2) ^ swz)));
            float bv = bf2f(*(const unsigned short*)(act + row * 512 + 256 + ((k * 2) ^ swz)));
            rs0 += av * W3f[k * 3 + 0]; rs1 += av * W3f[k * 3 + 1]; rs2 += av * W3f[k * 3 + 2];
            sh0 += bv * W3f[192 + k * 3 + 0]; sh1 += bv * W3f[192 + k * 3 + 1]; sh2 += bv * W3f[192 + k * 3 + 2];
        }
        rs0 += __shfl_xor(rs0, 1); rs0 += __shfl_xor(rs0, 2);
        rs1 += __shfl_xor(rs1, 1); rs1 += __shfl_xor(rs1, 2);
        rs2 += __shfl_xor(rs2, 1); rs2 += __shfl_xor(rs2, 2);
        sh0 += __shfl_xor(sh0, 1); sh0 += __shfl_xor(sh0, 2);
        sh1 += __shfl_xor(sh1, 1); sh1 += __shfl_xor(sh1, 2);
        sh2 += __shfl_xor(sh2, 1); sh2 += __shfl_xor(sh2, 2);
        if (sub == 0) {
            size_t node = row0 + row;
            bool coup = (types[node] > 0) && !maskb[node];
            float c0 = coords[node * 3 + 0], c1 = coords[node * 3 + 1], c2 = coords[node * 3 + 2];
            float ls0 = 0.f, ls1 = 0.f, ls2 = 0.f, o0 = c0, o1 = c1, o2 = c2;
            if (coup) {
                ls0 = tanhf(rs0 + bs3[0]) * 0.5f;
                ls1 = tanhf(rs1 + bs3[1]) * 0.5f;
                ls2 = tanhf(rs2 + bs3[2]) * 0.5f;
                o0 = expf(ls0) * c0 + sh0 + bt3[0];
                o1 = expf(ls1) * c1 + sh1 + bt3[1];
                o2 = expf(ls2) * c2 + sh2 + bt3[2];
            }
            outc[node * 3 + 0] = o0;
            outc[node * 3 + 1] = o1;
            outc[node * 3 + 2] = o2;
            red[row] = ls0 + ls1 + ls2;
        }
    }
    __syncthreads();
    for (int s = 32; s > 0; s >>= 1) {
        if (tx < s) red[tx] += red[tx + s];
        __syncthreads();
    }
    if (tx == 0) partial[blockIdx.x] = red[0];
}

__global__ void red_k(const float* __restrict__ partial, float* __restrict__ ldet)
{
    __shared__ float s[1024];
    int t = threadIdx.x;
#pragma unroll
    for (int p = 0; p < 4; ++p) s[t + p * 256] = partial[t + p * 256];
    __syncthreads();
    if (t < 16) {
        float v = 0.f;
        for (int i = 0; i < 64; ++i) v += s[t * 64 + i];
        ldet[t] = v;       // 64 blocks x 64 rows = 4096 nodes per batch
    }
}

// ============================================================================================
extern "C" void kernel_launch(void* const* d_in, const int* in_sizes, int n_in,
                              void* d_out, int out_size, void* d_ws, size_t ws_size,
                              hipStream_t stream)
{
    (void)in_sizes; (void)n_in; (void)out_size; (void)ws_size;
    const float* coords = (const float*)d_in[0];
    const int*   types  = (const int*)d_in[1];
    const int*   adj    = (const int*)d_in[2];
    const int*   ebi    = (const int*)d_in[3];
    const unsigned char* maskb = (const unsigned char*)d_in[4];
    const float* embed  = (const float*)d_in[5];
    const float* W_in   = (const float*)d_in[6];
    const float* b_in   = (const float*)d_in[7];
    const float* W_msg[2] = {(const float*)d_in[8],  (const float*)d_in[12]};
    const float* b_msg[2] = {(const float*)d_in[9],  (const float*)d_in[13]};
    const float* W_upd[2] = {(const float*)d_in[10], (const float*)d_in[14]};
    const float* b_upd[2] = {(const float*)d_in[11], (const float*)d_in[15]};
    const float* W_out = (const float*)d_in[16]; const float* b_out = (const float*)d_in[17];
    const float* Ws0 = (const float*)d_in[18]; const float* bs0 = (const float*)d_in[19];
    const float* Ws1 = (const float*)d_in[20]; const float* bs1 = (const float*)d_in[21];
    const float* Ws2 = (const float*)d_in[22]; const float* bs2 = (const float*)d_in[23];
    const float* Ws3 = (const float*)d_in[24]; const float* bs3 = (const float*)d_in[25];
    const float* Wt0 = (const float*)d_in[26]; const float* bt0 = (const float*)d_in[27];
    const float* Wt1 = (const float*)d_in[28]; const float* bt1 = (const float*)d_in[29];
    const float* Wt2 = (const float*)d_in[30]; const float* bt2 = (const float*)d_in[31];
    const float* Wt3 = (const float*)d_in[32]; const float* bt3 = (const float*)d_in[33];

    char* ws = (char*)d_ws;
    size_t off = 0;
    auto alloc = [&](size_t bytes) { void* p = ws + off; off += (bytes + 255) & ~(size_t)255; return p; };
    unsigned short* hf   = (unsigned short*)alloc((size_t)NNODE * 128 * 2);
    unsigned short* P12  = (unsigned short*)alloc((size_t)NNODE * 256 * 2);
    unsigned short* agg  = (unsigned short*)alloc((size_t)NNODE * 128 * 2);
    int*   deg  = (int*)alloc((size_t)NNODE * 4);
    int*   offs = (int*)alloc((size_t)(NNODE + 1) * 4);
    int*   cur  = (int*)alloc((size_t)NNODE * 4);
    int*   esrc = (int*)alloc((size_t)NE * 4);
    unsigned short* Btm0 = (unsigned short*)alloc(256 * 128 * 2);
    unsigned short* Btm1 = (unsigned short*)alloc(256 * 128 * 2);
    unsigned short* Btu0 = (unsigned short*)alloc(128 * 256 * 2);
    unsigned short* Btu1 = (unsigned short*)alloc(128 * 256 * 2);
    unsigned short* WoutP  = (unsigned short*)alloc(128 * 128 * 2);
    unsigned short* Bt0cat = (unsigned short*)alloc(256 * 192 * 2);
    unsigned short* Bt1cat = (unsigned short*)alloc(256 * 128 * 2);
    unsigned short* Bt2cat = (unsigned short*)alloc(256 * 128 * 2);
    float* b0cat  = (float*)alloc(256 * 4);
    float* b1cat  = (float*)alloc(256 * 4);
    float* b2cat  = (float*)alloc(256 * 4);
    float* bm0cat = (float*)alloc(256 * 4);
    float* bm1cat = (float*)alloc(256 * 4);
    float* partial = (float*)alloc(1024 * 4);

    hipMemsetAsync(deg, 0, (size_t)NNODE * 4, stream);
    hipMemsetAsync(cur, 0, (size_t)NNODE * 4, stream);

    deg_k<<<NE / 256, 256, 0, stream>>>(adj, ebi, deg);
    scan_k<<<1, 1024, 0, stream>>>(deg, offs);
    scat_k<<<NE / 256, 256, 0, stream>>>(adj, ebi, offs, cur, esrc);
    prep_k<<<1029, 256, 0, stream>>>(W_msg[0], W_msg[1], W_upd[0], W_upd[1], W_out,
                                     Ws0, Wt0, Ws1, Wt1, Ws2, Wt2,
                                     bs0, bt0, bs1, bt1, bs2, bt2, b_msg[0], b_msg[1],
                                     Btm0, Btm1, Btu0, Btu1, WoutP,
                                     Bt0cat, Bt1cat, Bt2cat,
                                     b0cat, b1cat, b2cat, bm0cat, bm1cat);

    fused_im_k<<<1024, 256, 0, stream>>>(types, coords, maskb, embed, W_in, b_in,
                                         Btm0, bm0cat, hf, P12);
    agg_k<<<NNODE / 4, 256, 0, stream>>>(P12, offs, esrc, agg);
    fused_um_k<<<1024, 256, 0, stream>>>(hf, agg, Btu0, b_upd[0], Btm1, bm1cat, hf, P12);
    agg_k<<<NNODE / 4, 256, 0, stream>>>(P12, offs, esrc, agg);

    float* outc = (float*)d_out;
    fused_ut_k<<<1024, 256, 0, stream>>>(hf, agg, Btu1, b_upd[1], WoutP, b_out,
                                         Bt0cat, b0cat, Bt1cat, b1cat, Bt2cat, b2cat,
                                         Ws3, bs3, Wt3, bt3,
                                         coords, types, maskb, outc, partial);
    red_k<<<1, 256, 0, stream>>>(partial, outc + (size_t)NNODE * 3);
}